// Round 19
// baseline (327.350 us; speedup 1.0000x reference)
//
#include <hip/hip_runtime.h>

#define NN 100000
#define NE 1600000
#define EN (NE + NN)          // edges incl. self-loops
#define FIN 128
#define H1 8
#define C1 16
#define F1 128                // H1*C1
#define NC 64
#define NEG 0.2f

// ---- CSR-build multisplit parameters ----
#define BSH 7                 // bucket = dst >> BSH
#define BKN 128               // nodes per bucket
#define NBUK ((NN + BKN - 1) / BKN)   // 782
#define NBLK 256              // edge-chunk blocks for P1/P2
#define CHUNK ((EN + NBLK - 1) / NBLK) // 6641
// XCD-aware chunk swizzle (kept from r17; neutral but harmless)
__device__ __forceinline__ int chunk_of_block(int b) {
  return (b & 7) * (NBLK / 8) + (b >> 3);
}

typedef unsigned short ushort_t;
typedef unsigned int uint_t;
typedef __attribute__((ext_vector_type(8))) short short8v;
typedef __attribute__((ext_vector_type(4))) float f32x4;
typedef __attribute__((ext_vector_type(2))) float f32x2;

union U8 { ushort_t u[8]; short8v v; uint4 q; };

__device__ __forceinline__ ushort_t f2bf(float f) {
  uint_t u = __builtin_bit_cast(uint_t, f);
  u += 0x7FFF + ((u >> 16) & 1);  // RNE
  return (ushort_t)(u >> 16);
}
__device__ __forceinline__ float bflo(uint_t u) {
  return __builtin_bit_cast(float, u << 16);
}
__device__ __forceinline__ float bfhi(uint_t u) {
  return __builtin_bit_cast(float, u & 0xFFFF0000u);
}

// ---------------- fp8 encode/decode (HW cvt preferred) -----------------------
#if __has_builtin(__builtin_amdgcn_cvt_pk_fp8_f32) && \
    __has_builtin(__builtin_amdgcn_cvt_pk_f32_fp8)
__device__ __forceinline__ uint_t fp8_pack4(float f0, float f1, float f2,
                                            float f3) {
  int p = 0;
  p = __builtin_amdgcn_cvt_pk_fp8_f32(f0, f1, p, false);
  p = __builtin_amdgcn_cvt_pk_fp8_f32(f2, f3, p, true);
  return (uint_t)p;
}
__device__ __forceinline__ void fp8_unpack4(uint_t w, float* o) {
  f32x2 d0 = __builtin_amdgcn_cvt_pk_f32_fp8((int)w, false);
  f32x2 d1 = __builtin_amdgcn_cvt_pk_f32_fp8((int)w, true);
  o[0] = d0.x; o[1] = d0.y; o[2] = d1.x; o[3] = d1.y;
}
#else
__device__ __forceinline__ uint_t fp8_enc1(float f) {
  uint_t u = __builtin_bit_cast(uint_t, f);
  uint_t s = (u >> 24) & 0x80u;
  int e = (int)((u >> 23) & 0xFF) - 127;
  if (e < -9) return s;
  if (e < -6) {
    float af = __builtin_bit_cast(float, u & 0x7FFFFFFFu);
    uint_t m = (uint_t)(af * 512.f + 0.5f);
    return s | m;
  }
  uint_t mant = u & 0x7FFFFF;
  uint_t keep = mant >> 20;
  uint_t rest = mant & 0xFFFFF;
  keep += (rest > 0x80000u) || (rest == 0x80000u && (keep & 1));
  uint_t ee = (uint_t)(e + 7);
  if (keep == 8) { keep = 0; ee += 1; }
  if (ee > 15 || (ee == 15 && keep > 6)) return s | 0x7E;
  return s | (ee << 3) | keep;
}
__device__ __forceinline__ float fp8_dec1(uint_t b) {
  uint_t s = (b & 0x80u) << 24;
  uint_t e = (b >> 3) & 15u, m = b & 7u;
  if (e == 0) {
    float v = (float)m * (1.0f / 512.0f);
    return __builtin_bit_cast(float, s | __builtin_bit_cast(uint_t, v));
  }
  return __builtin_bit_cast(float, s | ((e + 120u) << 23) | (m << 20));
}
__device__ __forceinline__ uint_t fp8_pack4(float f0, float f1, float f2,
                                            float f3) {
  return fp8_enc1(f0) | (fp8_enc1(f1) << 8) | (fp8_enc1(f2) << 16) |
         (fp8_enc1(f3) << 24);
}
__device__ __forceinline__ void fp8_unpack4(uint_t w, float* o) {
  o[0] = fp8_dec1(w & 0xFF); o[1] = fp8_dec1((w >> 8) & 0xFF);
  o[2] = fp8_dec1((w >> 16) & 0xFF); o[3] = fp8_dec1(w >> 24);
}
#endif

// ------------------ CSR P1: count (fused weight prep) ------------------------
__global__ __launch_bounds__(512) void bucket_count_kernel(
    const int* __restrict__ dstA, int* __restrict__ cnt,
    const float* __restrict__ W1, const float* __restrict__ W2,
    ushort_t* __restrict__ WT1, ushort_t* __restrict__ WT2) {
  __shared__ int histL[NBUK];
  int b = blockIdx.x, t = threadIdx.x;
  int gid = b * 512 + t;
  if (gid < 128 * 128) {
    int n = gid >> 7, k = gid & 127;
    int c = (n & 15) * 8 + (n >> 4);
    WT1[gid] = f2bf(W1[k * 128 + c]);
  } else if (gid < 128 * 128 + 64 * 128) {
    int j = gid - 128 * 128;
    int n = j >> 7, k = j & 127;
    int c = (n & 15) * 4 + (n >> 4);
    WT2[j] = f2bf(W2[k * 64 + c]);
  }
  for (int i = t; i < NBUK; i += 512) histL[i] = 0;
  __syncthreads();
  int ch = chunk_of_block(b);
  int e0 = ch * CHUNK, e1 = min(e0 + CHUNK, EN);
  for (int e = e0 + t; e < e1; e += 512) {
    int d = (e < NE) ? dstA[e] : (e - NE);
    atomicAdd(&histL[d >> BSH], 1);
  }
  __syncthreads();
  for (int i = t; i < NBUK; i += 512) cnt[i * NBLK + ch] = histL[i];
}

// scan: per-bucket column scan over chunks, then serial bucket prefix.
__global__ __launch_bounds__(256) void bucket_scan_kernel(
    int* __restrict__ cnt, int* __restrict__ bucket_base) {
  __shared__ int colsum[NBUK];
  int t = threadIdx.x;
  for (int j = t; j < NBUK; j += 256) {
    int run = 0;
    int* c = cnt + j * NBLK;
    for (int b = 0; b < NBLK; ++b) { int v = c[b]; c[b] = run; run += v; }
    colsum[j] = run;
  }
  __syncthreads();
  if (t == 0) {
    int base = 0;
    for (int j = 0; j < NBUK; ++j) {
      bucket_base[j] = base;
      int v = colsum[j];
      colsum[j] = base;
      base += v;
    }
    bucket_base[NBUK] = base;  // == EN
  }
  __syncthreads();
  for (int j = t; j < NBUK; j += 256) {
    int bb = colsum[j];
    int* c = cnt + j * NBLK;
    for (int b = 0; b < NBLK; ++b) c[b] += bb;
  }
}

// ---- HORIZONTAL FUSION: blocks [0,NBLK) scatter edges; rest run gemm1 -------
__global__ __launch_bounds__(512) void scatter_gemm1_kernel(
    const int* __restrict__ srcA, const int* __restrict__ dstA,
    const int* __restrict__ cnt, int* __restrict__ staging,
    const float* __restrict__ X, const ushort_t* __restrict__ WT1,
    const float* __restrict__ a_src, const float* __restrict__ a_dst,
    uint2* __restrict__ h8, float* __restrict__ asn, float* __restrict__ adn,
    int nrows) {
  __shared__ int cur[NBUK];
  if (blockIdx.x < NBLK) {
    int b = blockIdx.x, t = threadIdx.x;
    int ch = chunk_of_block(b);
    for (int i = t; i < NBUK; i += 512) cur[i] = cnt[i * NBLK + ch];
    __syncthreads();
    int e0 = ch * CHUNK, e1 = min(e0 + CHUNK, EN);
    for (int e = e0 + t; e < e1; e += 512) {
      int s, d;
      if (e < NE) { s = srcA[e]; d = dstA[e]; } else { s = e - NE; d = s; }
      int pos = atomicAdd(&cur[d >> BSH], 1);
      staging[pos] = s | ((d & (BKN - 1)) << 17);
    }
    return;
  }
  // ---------------- MFMA GEMM1 (fused layer-1 prep) ----------------
  const int tid = threadIdx.x;
  const int wave = tid >> 6, lane = tid & 63;
  const int row0 = (blockIdx.x - NBLK) * 128 + wave * 16;
  const int rlo = lane & 15, khi = lane >> 4;  // khi in 0..3

  f32x4 acc[8];
#pragma unroll
  for (int n = 0; n < 8; ++n) acc[n] = (f32x4){0.f, 0.f, 0.f, 0.f};

#pragma unroll
  for (int ks = 0; ks < 4; ++ks) {
    const int kk = ks * 32 + khi * 8;
    int row = row0 + rlo;
    if (row >= nrows) row = nrows - 1;
    const float4* xp = (const float4*)(X + (size_t)row * 128 + kk);
    float4 u = xp[0], v = xp[1];
    U8 t;
    t.u[0] = f2bf(u.x); t.u[1] = f2bf(u.y); t.u[2] = f2bf(u.z); t.u[3] = f2bf(u.w);
    t.u[4] = f2bf(v.x); t.u[5] = f2bf(v.y); t.u[6] = f2bf(v.z); t.u[7] = f2bf(v.w);
    short8v a = t.v;
#pragma unroll
    for (int nf = 0; nf < 8; ++nf) {
      short8v b = *(const short8v*)(WT1 + (nf * 16 + rlo) * 128 + kk);
      acc[nf] = __builtin_amdgcn_mfma_f32_16x16x32_bf16(a, b, acc[nf], 0, 0, 0);
    }
  }
  const float4* as4 = (const float4*)a_src;
  const float4* ad4 = (const float4*)a_dst;
  float4 as0 = as4[rlo * 2], as1 = as4[rlo * 2 + 1];
  float4 ad0 = ad4[rlo * 2], ad1 = ad4[rlo * 2 + 1];
  // C/D layout: col = lane&15, row = (lane>>4)*4 + reg  [m89-verified]
  int rbase = row0 + khi * 4;
#pragma unroll
  for (int r = 0; r < 4; ++r) {
    int row = rbase + r;
    bool ok = (row < nrows);
    uint2 pk;
    pk.x = fp8_pack4(acc[0][r], acc[1][r], acc[2][r], acc[3][r]);
    pk.y = fp8_pack4(acc[4][r], acc[5][r], acc[6][r], acc[7][r]);
    if (ok) h8[(size_t)row * 16 + rlo] = pk;
    float s = acc[0][r] * as0.x + acc[1][r] * as0.y +
              acc[2][r] * as0.z + acc[3][r] * as0.w +
              acc[4][r] * as1.x + acc[5][r] * as1.y +
              acc[6][r] * as1.z + acc[7][r] * as1.w;
    float d = acc[0][r] * ad0.x + acc[1][r] * ad0.y +
              acc[2][r] * ad0.z + acc[3][r] * ad0.w +
              acc[4][r] * ad1.x + acc[5][r] * ad1.y +
              acc[6][r] * ad1.z + acc[7][r] * ad1.w;
    s += __shfl_xor(s, 1);
    d += __shfl_xor(d, 1);
    if (ok && (rlo & 1) == 0) {
      asn[row * 8 + (rlo >> 1)] = s;
      adn[row * 8 + (rlo >> 1)] = d;
    }
  }
}

// ---- FUSED fine-CSR + layer-1 gather: one block per 128-node bucket ---------
// Phase 1: histogram -> 128-wide scan -> rp write -> cursor scatter (col).
// Phase 2: gather1 for this bucket's 128 nodes; col slice is L2-hot and node
// bounds come from LDS (startL), no rp re-read.
__global__ __launch_bounds__(512) void csr_gather1_kernel(
    const int* __restrict__ staging, const int* __restrict__ bucket_base,
    int* __restrict__ rp, int* __restrict__ col,
    const float* __restrict__ asn, const float* __restrict__ adn,
    const uint4* __restrict__ h8, const float* __restrict__ b1,
    ushort_t* __restrict__ x2) {
  __shared__ int degL[BKN];
  __shared__ int curL[BKN];
  __shared__ int startL[BKN + 1];
  __shared__ int sdata[2][BKN];
  int bk = blockIdx.x, t = threadIdx.x;
  int ebase = bucket_base[bk], eend = bucket_base[bk + 1];
  int ecnt = eend - ebase;
  if (t < BKN) degL[t] = 0;
  __syncthreads();
  for (int e = t; e < ecnt; e += 512)
    atomicAdd(&degL[staging[ebase + e] >> 17], 1);
  __syncthreads();
  if (t < BKN) sdata[0][t] = degL[t];
  __syncthreads();
  int sp = 0;
  for (int off = 1; off < BKN; off <<= 1) {
    if (t < BKN) {
      int val = sdata[sp][t];
      if (t >= off) val += sdata[sp][t - off];
      sdata[sp ^ 1][t] = val;
    }
    __syncthreads();
    sp ^= 1;
  }
  if (t < BKN) {
    int ex = sdata[sp][t] - degL[t];  // exclusive
    curL[t] = ex;
    startL[t] = ebase + ex;
    int node = bk * BKN + t;
    if (node < NN) rp[node] = ebase + ex;
  }
  if (t == 0) startL[BKN] = eend;
  if (bk == 0 && t == 0) rp[NN] = EN;
  __syncthreads();
  for (int e = t; e < ecnt; e += 512) {
    int pk = staging[ebase + e];
    int pos = atomicAdd(&curL[pk >> 17], 1);
    col[ebase + pos] = pk & 0x1FFFF;
  }
  __syncthreads();
  // ---- phase 2: gather1 (8 lanes/node, lane = head); 64 nodes per pass ----
  int g = t >> 3, lane = t & 7;
#pragma unroll
  for (int pass = 0; pass < 2; ++pass) {
    int i = pass * 64 + g;
    int node = bk * BKN + i;
    if (node >= NN) continue;
    float aD = adn[node * 8 + lane];
    int p = startL[i], p1 = startL[i + 1];
    float a[16];
#pragma unroll
    for (int j = 0; j < 16; ++j) a[j] = 0.f;
    float den = 0.f;
    for (; p + 1 < p1; p += 2) {
      int s0 = col[p], s1 = col[p + 1];
      float e0 = asn[s0 * 8 + lane] + aD;
      float e1 = asn[s1 * 8 + lane] + aD;
      uint4 q0 = h8[(size_t)s0 * 8 + lane];
      uint4 q1 = h8[(size_t)s1 * 8 + lane];
      e0 = e0 > 0.f ? e0 : NEG * e0;
      e1 = e1 > 0.f ? e1 : NEG * e1;
      float ee0 = __expf(e0), ee1 = __expf(e1);
      float d0[4], d1[4], d2[4], d3[4];
      fp8_unpack4(q0.x, d0); fp8_unpack4(q0.y, d1);
      fp8_unpack4(q0.z, d2); fp8_unpack4(q0.w, d3);
      float g0[4], g1[4], g2[4], g3[4];
      fp8_unpack4(q1.x, g0); fp8_unpack4(q1.y, g1);
      fp8_unpack4(q1.z, g2); fp8_unpack4(q1.w, g3);
#pragma unroll
      for (int j = 0; j < 4; ++j) {
        a[j]      += ee0 * d0[j] + ee1 * g0[j];
        a[4 + j]  += ee0 * d1[j] + ee1 * g1[j];
        a[8 + j]  += ee0 * d2[j] + ee1 * g2[j];
        a[12 + j] += ee0 * d3[j] + ee1 * g3[j];
      }
      den += ee0 + ee1;
    }
    if (p < p1) {
      int s0 = col[p];
      float e0 = asn[s0 * 8 + lane] + aD;
      uint4 q0 = h8[(size_t)s0 * 8 + lane];
      e0 = e0 > 0.f ? e0 : NEG * e0;
      float ee0 = __expf(e0);
      float d0[4], d1[4], d2[4], d3[4];
      fp8_unpack4(q0.x, d0); fp8_unpack4(q0.y, d1);
      fp8_unpack4(q0.z, d2); fp8_unpack4(q0.w, d3);
#pragma unroll
      for (int j = 0; j < 4; ++j) {
        a[j] += ee0 * d0[j];
        a[4 + j] += ee0 * d1[j];
        a[8 + j] += ee0 * d2[j];
        a[12 + j] += ee0 * d3[j];
      }
      den += ee0;
    }
    float inv = 1.f / den;
    const float4* b4 = (const float4*)b1;  // channels 16*lane + 0..15
    U8 t0, t1;
#pragma unroll
    for (int h = 0; h < 4; ++h) {
      float4 bv = b4[lane * 4 + h];
      float o0 = fmaf(a[h * 4 + 0], inv, bv.x);
      float o1 = fmaf(a[h * 4 + 1], inv, bv.y);
      float o2 = fmaf(a[h * 4 + 2], inv, bv.z);
      float o3 = fmaf(a[h * 4 + 3], inv, bv.w);
      o0 = o0 > 0.f ? o0 : __expf(o0) - 1.f;
      o1 = o1 > 0.f ? o1 : __expf(o1) - 1.f;
      o2 = o2 > 0.f ? o2 : __expf(o2) - 1.f;
      o3 = o3 > 0.f ? o3 : __expf(o3) - 1.f;
      U8& tt = (h < 2) ? t0 : t1;
      int base = (h & 1) * 4;
      tt.u[base + 0] = f2bf(o0); tt.u[base + 1] = f2bf(o1);
      tt.u[base + 2] = f2bf(o2); tt.u[base + 3] = f2bf(o3);
    }
    uint4* xr = (uint4*)(x2 + (size_t)node * F1);  // row = 8 uint4
    xr[lane * 2 + 0] = t0.q;
    xr[lane * 2 + 1] = t1.q;
  }
}

// ---------- MFMA GEMM2 (fused layer-2 prep; no LDS, B from WT2) --------------
__global__ __launch_bounds__(256) void mfma_gemm2_kernel(
    const ushort_t* __restrict__ X2, const ushort_t* __restrict__ WT2,
    const float* __restrict__ a_src, const float* __restrict__ a_dst,
    uint_t* __restrict__ h28, float* __restrict__ asn, float* __restrict__ adn,
    int nrows) {
  const int tid = threadIdx.x;
  const int wave = tid >> 6, lane = tid & 63;
  const int row0 = blockIdx.x * 64 + wave * 16;
  const int rlo = lane & 15, khi = lane >> 4;

  f32x4 acc[4];
#pragma unroll
  for (int n = 0; n < 4; ++n) acc[n] = (f32x4){0.f, 0.f, 0.f, 0.f};

#pragma unroll
  for (int ks = 0; ks < 4; ++ks) {
    const int kk = ks * 32 + khi * 8;
    int row = row0 + rlo;
    if (row >= nrows) row = nrows - 1;
    U8 t;
    t.q = *(const uint4*)(X2 + (size_t)row * 128 + kk);
    short8v a = t.v;
#pragma unroll
    for (int nf = 0; nf < 4; ++nf) {
      short8v b = *(const short8v*)(WT2 + (nf * 16 + rlo) * 128 + kk);
      acc[nf] = __builtin_amdgcn_mfma_f32_16x16x32_bf16(a, b, acc[nf], 0, 0, 0);
    }
  }
  float4 as = ((const float4*)a_src)[rlo];
  float4 ad = ((const float4*)a_dst)[rlo];
  int rbase = row0 + khi * 4;
#pragma unroll
  for (int r = 0; r < 4; ++r) {
    int row = rbase + r;
    bool ok = (row < nrows);
    uint_t pk = fp8_pack4(acc[0][r], acc[1][r], acc[2][r], acc[3][r]);
    if (ok) h28[(size_t)row * 16 + rlo] = pk;
    float s = acc[0][r] * as.x + acc[1][r] * as.y +
              acc[2][r] * as.z + acc[3][r] * as.w;
    float d = acc[0][r] * ad.x + acc[1][r] * ad.y +
              acc[2][r] * ad.z + acc[3][r] * ad.w;
    s += __shfl_xor(s, 1); s += __shfl_xor(s, 2);
    s += __shfl_xor(s, 4); s += __shfl_xor(s, 8);
    d += __shfl_xor(d, 1); d += __shfl_xor(d, 2);
    d += __shfl_xor(d, 4); d += __shfl_xor(d, 8);
    if (ok && rlo == 0) { asn[row] = s; adn[row] = d; }
  }
}

// ------ layer-2 gather: 8 lanes/node, 2-edge unroll + log_softmax ------------
__global__ __launch_bounds__(256) void gather2_kernel(
    const int* __restrict__ rp, const int* __restrict__ col,
    const float* __restrict__ asn, const float* __restrict__ adn,
    const uint2* __restrict__ h28, const float* __restrict__ b2,
    float* __restrict__ out) {
  int node = (blockIdx.x << 5) + (threadIdx.x >> 3);
  if (node >= NN) return;
  int lane = threadIdx.x & 7;
  float aD = adn[node];
  int p = rp[node], p1 = rp[node + 1];
  float a[8];
#pragma unroll
  for (int j = 0; j < 8; ++j) a[j] = 0.f;
  float den = 0.f;

  for (; p + 1 < p1; p += 2) {
    int s0 = col[p], s1 = col[p + 1];
    float e0 = asn[s0] + aD;
    float e1 = asn[s1] + aD;
    uint2 q0 = h28[(size_t)s0 * 8 + lane];
    uint2 q1 = h28[(size_t)s1 * 8 + lane];
    e0 = e0 > 0.f ? e0 : NEG * e0;
    e1 = e1 > 0.f ? e1 : NEG * e1;
    float ee0 = __expf(e0), ee1 = __expf(e1);
    float d0[4], d1[4], g0[4], g1[4];
    fp8_unpack4(q0.x, d0); fp8_unpack4(q0.y, d1);
    fp8_unpack4(q1.x, g0); fp8_unpack4(q1.y, g1);
#pragma unroll
    for (int j = 0; j < 4; ++j) {
      a[j] += ee0 * d0[j] + ee1 * g0[j];
      a[4 + j] += ee0 * d1[j] + ee1 * g1[j];
    }
    den += ee0 + ee1;
  }
  if (p < p1) {
    int s0 = col[p];
    float e0 = asn[s0] + aD;
    uint2 q0 = h28[(size_t)s0 * 8 + lane];
    e0 = e0 > 0.f ? e0 : NEG * e0;
    float ee0 = __expf(e0);
    float d0[4], d1[4];
    fp8_unpack4(q0.x, d0); fp8_unpack4(q0.y, d1);
#pragma unroll
    for (int j = 0; j < 4; ++j) {
      a[j] += ee0 * d0[j];
      a[4 + j] += ee0 * d1[j];
    }
    den += ee0;
  }
  float inv = 1.f / den;
  float4 bv0 = ((const float4*)b2)[lane * 2 + 0];
  float4 bv1 = ((const float4*)b2)[lane * 2 + 1];
  float v[8];
  v[0] = fmaf(a[0], inv, bv0.x); v[1] = fmaf(a[1], inv, bv0.y);
  v[2] = fmaf(a[2], inv, bv0.z); v[3] = fmaf(a[3], inv, bv0.w);
  v[4] = fmaf(a[4], inv, bv1.x); v[5] = fmaf(a[5], inv, bv1.y);
  v[6] = fmaf(a[6], inv, bv1.z); v[7] = fmaf(a[7], inv, bv1.w);
  float m = v[0];
#pragma unroll
  for (int j = 1; j < 8; ++j) m = fmaxf(m, v[j]);
#pragma unroll
  for (int k = 1; k < 8; k <<= 1) m = fmaxf(m, __shfl_xor(m, k));
  float ex = 0.f;
#pragma unroll
  for (int j = 0; j < 8; ++j) ex += __expf(v[j] - m);
#pragma unroll
  for (int k = 1; k < 8; k <<= 1) ex += __shfl_xor(ex, k);
  float lse = m + __logf(ex);
  float4 r0 = {v[0] - lse, v[1] - lse, v[2] - lse, v[3] - lse};
  float4 r1 = {v[4] - lse, v[5] - lse, v[6] - lse, v[7] - lse};
  float4* orow = (float4*)(out + (size_t)node * NC);
  orow[lane * 2 + 0] = r0;
  orow[lane * 2 + 1] = r1;
}

extern "C" void kernel_launch(void* const* d_in, const int* in_sizes, int n_in,
                              void* d_out, int out_size, void* d_ws,
                              size_t ws_size, hipStream_t stream) {
  const float* x = (const float*)d_in[0];
  const int* edge_index = (const int*)d_in[1];
  const float* W1 = (const float*)d_in[2];
  const float* a_src1 = (const float*)d_in[3];
  const float* a_dst1 = (const float*)d_in[4];
  const float* b1 = (const float*)d_in[5];
  const float* W2 = (const float*)d_in[6];
  const float* a_src2 = (const float*)d_in[7];
  const float* a_dst2 = (const float*)d_in[8];
  const float* b2 = (const float*)d_in[9];
  float* out = (float*)d_out;
  float* ws = (float*)d_ws;

  // workspace layout (float offsets), non-overlapping:
  ushort_t* x2b = (ushort_t*)ws;               // [0, 6.4M)   bf16 x2
  uint4* h8 = (uint4*)(ws + 6400000);          // [6.4M, 9.6M)  fp8 h1 (linear)
  uint2* h28 = (uint2*)(ws + 9600000);         // [9.6M, 11.2M) fp8 h2 (linear)
  float* asn1 = ws + 11200000;                 // [11.2M, 12.0M)
  float* adn1 = ws + 12000000;                 // [12.0M, 12.8M)
  float* asn2 = ws + 12800000;                 // [12.8M, 12.9M)
  float* adn2 = ws + 12900000;                 // [12.9M, 13.0M)
  ushort_t* WT1 = (ushort_t*)(ws + 13000000);  // 16384 bf16
  ushort_t* WT2 = (ushort_t*)(ws + 13010000);  // 8192 bf16
  int* rp = (int*)(ws + 13020000);             // NN+1
  int* col = rp + NN + 1;                      // EN
  int* staging = col + EN;                     // EN
  int* cnt = staging + EN;                     // NBUK*NBLK = 200192
  int* bucket_base = cnt + NBUK * NBLK;        // NBUK+1  (~16.9M floats)

  const int* srcA = edge_index;
  const int* dstA = edge_index + NE;

  // ---- CSR P1 (fused wt_prep) + scan ----
  bucket_count_kernel<<<NBLK, 512, 0, stream>>>(dstA, cnt, W1, W2, WT1, WT2);
  bucket_scan_kernel<<<1, 256, 0, stream>>>(cnt, bucket_base);
  // ---- scatter || gemm1 (horizontal fusion) ----
  scatter_gemm1_kernel<<<NBLK + (NN + 127) / 128, 512, 0, stream>>>(
      srcA, dstA, cnt, staging, x, WT1, a_src1, a_dst1, (uint2*)h8, asn1, adn1,
      NN);
  // ---- fused fine-CSR + layer-1 gather (one block per 128-node bucket) ----
  csr_gather1_kernel<<<NBUK, 512, 0, stream>>>(staging, bucket_base, rp, col,
                                               asn1, adn1, h8, b1, x2b);
  // ---- layer 2 ----
  mfma_gemm2_kernel<<<(NN + 63) / 64, 256, 0, stream>>>(
      x2b, WT2, a_src2, a_dst2, (uint_t*)h28, asn2, adn2, NN);
  gather2_kernel<<<(NN + 31) / 32, 256, 0, stream>>>(rp, col, asn2, adn2, h28,
                                                     b2, out);
}

// Round 20
// 196.650 us; speedup vs baseline: 1.6646x; 1.6646x over previous
//
#include <hip/hip_runtime.h>

#define NN 100000
#define NE 1600000
#define EN (NE + NN)          // edges incl. self-loops
#define FIN 128
#define H1 8
#define C1 16
#define F1 128                // H1*C1
#define NC 64
#define NEG 0.2f

// ---- CSR-build multisplit parameters ----
#define BSH 7                 // bucket = dst >> BSH
#define BKN 128               // nodes per bucket
#define NBUK ((NN + BKN - 1) / BKN)   // 782
#define NBLK 256              // edge-chunk blocks for P1/P2
#define CHUNK ((EN + NBLK - 1) / NBLK) // 6641
// XCD-aware chunk swizzle (kept from r17; neutral but harmless)
__device__ __forceinline__ int chunk_of_block(int b) {
  return (b & 7) * (NBLK / 8) + (b >> 3);
}

typedef unsigned short ushort_t;
typedef unsigned int uint_t;
typedef __attribute__((ext_vector_type(8))) short short8v;
typedef __attribute__((ext_vector_type(4))) float f32x4;
typedef __attribute__((ext_vector_type(2))) float f32x2;

union U8 { ushort_t u[8]; short8v v; uint4 q; };

__device__ __forceinline__ ushort_t f2bf(float f) {
  uint_t u = __builtin_bit_cast(uint_t, f);
  u += 0x7FFF + ((u >> 16) & 1);  // RNE
  return (ushort_t)(u >> 16);
}
__device__ __forceinline__ float bflo(uint_t u) {
  return __builtin_bit_cast(float, u << 16);
}
__device__ __forceinline__ float bfhi(uint_t u) {
  return __builtin_bit_cast(float, u & 0xFFFF0000u);
}

// ---------------- fp8 encode/decode (HW cvt preferred) -----------------------
#if __has_builtin(__builtin_amdgcn_cvt_pk_fp8_f32) && \
    __has_builtin(__builtin_amdgcn_cvt_pk_f32_fp8)
__device__ __forceinline__ uint_t fp8_pack4(float f0, float f1, float f2,
                                            float f3) {
  int p = 0;
  p = __builtin_amdgcn_cvt_pk_fp8_f32(f0, f1, p, false);
  p = __builtin_amdgcn_cvt_pk_fp8_f32(f2, f3, p, true);
  return (uint_t)p;
}
__device__ __forceinline__ void fp8_unpack4(uint_t w, float* o) {
  f32x2 d0 = __builtin_amdgcn_cvt_pk_f32_fp8((int)w, false);
  f32x2 d1 = __builtin_amdgcn_cvt_pk_f32_fp8((int)w, true);
  o[0] = d0.x; o[1] = d0.y; o[2] = d1.x; o[3] = d1.y;
}
#else
__device__ __forceinline__ uint_t fp8_enc1(float f) {
  uint_t u = __builtin_bit_cast(uint_t, f);
  uint_t s = (u >> 24) & 0x80u;
  int e = (int)((u >> 23) & 0xFF) - 127;
  if (e < -9) return s;
  if (e < -6) {
    float af = __builtin_bit_cast(float, u & 0x7FFFFFFFu);
    uint_t m = (uint_t)(af * 512.f + 0.5f);
    return s | m;
  }
  uint_t mant = u & 0x7FFFFF;
  uint_t keep = mant >> 20;
  uint_t rest = mant & 0xFFFFF;
  keep += (rest > 0x80000u) || (rest == 0x80000u && (keep & 1));
  uint_t ee = (uint_t)(e + 7);
  if (keep == 8) { keep = 0; ee += 1; }
  if (ee > 15 || (ee == 15 && keep > 6)) return s | 0x7E;
  return s | (ee << 3) | keep;
}
__device__ __forceinline__ float fp8_dec1(uint_t b) {
  uint_t s = (b & 0x80u) << 24;
  uint_t e = (b >> 3) & 15u, m = b & 7u;
  if (e == 0) {
    float v = (float)m * (1.0f / 512.0f);
    return __builtin_bit_cast(float, s | __builtin_bit_cast(uint_t, v));
  }
  return __builtin_bit_cast(float, s | ((e + 120u) << 23) | (m << 20));
}
__device__ __forceinline__ uint_t fp8_pack4(float f0, float f1, float f2,
                                            float f3) {
  return fp8_enc1(f0) | (fp8_enc1(f1) << 8) | (fp8_enc1(f2) << 16) |
         (fp8_enc1(f3) << 24);
}
__device__ __forceinline__ void fp8_unpack4(uint_t w, float* o) {
  o[0] = fp8_dec1(w & 0xFF); o[1] = fp8_dec1((w >> 8) & 0xFF);
  o[2] = fp8_dec1((w >> 16) & 0xFF); o[3] = fp8_dec1(w >> 24);
}
#endif

// ------------------ CSR P1: count (fused weight prep) ------------------------
__global__ __launch_bounds__(512) void bucket_count_kernel(
    const int* __restrict__ dstA, int* __restrict__ cnt,
    const float* __restrict__ W1, const float* __restrict__ W2,
    ushort_t* __restrict__ WT1, ushort_t* __restrict__ WT2) {
  __shared__ int histL[NBUK];
  int b = blockIdx.x, t = threadIdx.x;
  int gid = b * 512 + t;
  if (gid < 128 * 128) {
    int n = gid >> 7, k = gid & 127;
    int c = (n & 15) * 8 + (n >> 4);
    WT1[gid] = f2bf(W1[k * 128 + c]);
  } else if (gid < 128 * 128 + 64 * 128) {
    int j = gid - 128 * 128;
    int n = j >> 7, k = j & 127;
    int c = (n & 15) * 4 + (n >> 4);
    WT2[j] = f2bf(W2[k * 64 + c]);
  }
  for (int i = t; i < NBUK; i += 512) histL[i] = 0;
  __syncthreads();
  int ch = chunk_of_block(b);
  int e0 = ch * CHUNK, e1 = min(e0 + CHUNK, EN);
  for (int e = e0 + t; e < e1; e += 512) {
    int d = (e < NE) ? dstA[e] : (e - NE);
    atomicAdd(&histL[d >> BSH], 1);
  }
  __syncthreads();
  for (int i = t; i < NBUK; i += 512) cnt[i * NBLK + ch] = histL[i];
}

// scan A: per-bucket 256-wide LDS scan over chunks (in place), emit colsum.
__global__ __launch_bounds__(256) void scan_chunks_kernel(
    int* __restrict__ cnt, int* __restrict__ colsum) {
  __shared__ int sd[2][256];
  int j = blockIdx.x, t = threadIdx.x;
  int v = cnt[j * NBLK + t];
  sd[0][t] = v;
  __syncthreads();
  int sp = 0;
  for (int off = 1; off < 256; off <<= 1) {
    int val = sd[sp][t];
    if (t >= off) val += sd[sp][t - off];
    sd[sp ^ 1][t] = val;
    __syncthreads();
    sp ^= 1;
  }
  cnt[j * NBLK + t] = sd[sp][t] - v;  // exclusive within bucket
  if (t == 255) colsum[j] = sd[sp][255];
}

// scan B: one block scans the NBUK colsums into bucket_base (NBUK <= 1024).
__global__ __launch_bounds__(1024) void scan_buckets_kernel(
    const int* __restrict__ colsum, int* __restrict__ bucket_base) {
  __shared__ int sd[2][1024];
  int t = threadIdx.x;
  int v = (t < NBUK) ? colsum[t] : 0;
  sd[0][t] = v;
  __syncthreads();
  int sp = 0;
  for (int off = 1; off < 1024; off <<= 1) {
    int val = sd[sp][t];
    if (t >= off) val += sd[sp][t - off];
    sd[sp ^ 1][t] = val;
    __syncthreads();
    sp ^= 1;
  }
  if (t < NBUK) bucket_base[t] = sd[sp][t] - v;
  if (t == 0) bucket_base[NBUK] = EN;
}

// ---- HORIZONTAL FUSION: blocks [0,NBLK) scatter edges; rest run gemm1 -------
// cursor = within-bucket exclusive (cnt) + bucket_base (added on load).
__global__ __launch_bounds__(512) void scatter_gemm1_kernel(
    const int* __restrict__ srcA, const int* __restrict__ dstA,
    const int* __restrict__ cnt, const int* __restrict__ bucket_base,
    int* __restrict__ staging,
    const float* __restrict__ X, const ushort_t* __restrict__ WT1,
    const float* __restrict__ a_src, const float* __restrict__ a_dst,
    uint2* __restrict__ h8, float* __restrict__ asn, float* __restrict__ adn,
    int nrows) {
  __shared__ int cur[NBUK];
  if (blockIdx.x < NBLK) {
    int b = blockIdx.x, t = threadIdx.x;
    int ch = chunk_of_block(b);
    for (int i = t; i < NBUK; i += 512)
      cur[i] = cnt[i * NBLK + ch] + bucket_base[i];
    __syncthreads();
    int e0 = ch * CHUNK, e1 = min(e0 + CHUNK, EN);
    for (int e = e0 + t; e < e1; e += 512) {
      int s, d;
      if (e < NE) { s = srcA[e]; d = dstA[e]; } else { s = e - NE; d = s; }
      int pos = atomicAdd(&cur[d >> BSH], 1);
      staging[pos] = s | ((d & (BKN - 1)) << 17);
    }
    return;
  }
  // ---------------- MFMA GEMM1 (fused layer-1 prep) ----------------
  const int tid = threadIdx.x;
  const int wave = tid >> 6, lane = tid & 63;
  const int row0 = (blockIdx.x - NBLK) * 128 + wave * 16;
  const int rlo = lane & 15, khi = lane >> 4;  // khi in 0..3

  f32x4 acc[8];
#pragma unroll
  for (int n = 0; n < 8; ++n) acc[n] = (f32x4){0.f, 0.f, 0.f, 0.f};

#pragma unroll
  for (int ks = 0; ks < 4; ++ks) {
    const int kk = ks * 32 + khi * 8;
    int row = row0 + rlo;
    if (row >= nrows) row = nrows - 1;
    const float4* xp = (const float4*)(X + (size_t)row * 128 + kk);
    float4 u = xp[0], v = xp[1];
    U8 t;
    t.u[0] = f2bf(u.x); t.u[1] = f2bf(u.y); t.u[2] = f2bf(u.z); t.u[3] = f2bf(u.w);
    t.u[4] = f2bf(v.x); t.u[5] = f2bf(v.y); t.u[6] = f2bf(v.z); t.u[7] = f2bf(v.w);
    short8v a = t.v;
#pragma unroll
    for (int nf = 0; nf < 8; ++nf) {
      short8v b = *(const short8v*)(WT1 + (nf * 16 + rlo) * 128 + kk);
      acc[nf] = __builtin_amdgcn_mfma_f32_16x16x32_bf16(a, b, acc[nf], 0, 0, 0);
    }
  }
  const float4* as4 = (const float4*)a_src;
  const float4* ad4 = (const float4*)a_dst;
  float4 as0 = as4[rlo * 2], as1 = as4[rlo * 2 + 1];
  float4 ad0 = ad4[rlo * 2], ad1 = ad4[rlo * 2 + 1];
  // C/D layout: col = lane&15, row = (lane>>4)*4 + reg  [m89-verified]
  int rbase = row0 + khi * 4;
#pragma unroll
  for (int r = 0; r < 4; ++r) {
    int row = rbase + r;
    bool ok = (row < nrows);
    uint2 pk;
    pk.x = fp8_pack4(acc[0][r], acc[1][r], acc[2][r], acc[3][r]);
    pk.y = fp8_pack4(acc[4][r], acc[5][r], acc[6][r], acc[7][r]);
    if (ok) h8[(size_t)row * 16 + rlo] = pk;
    float s = acc[0][r] * as0.x + acc[1][r] * as0.y +
              acc[2][r] * as0.z + acc[3][r] * as0.w +
              acc[4][r] * as1.x + acc[5][r] * as1.y +
              acc[6][r] * as1.z + acc[7][r] * as1.w;
    float d = acc[0][r] * ad0.x + acc[1][r] * ad0.y +
              acc[2][r] * ad0.z + acc[3][r] * ad0.w +
              acc[4][r] * ad1.x + acc[5][r] * ad1.y +
              acc[6][r] * ad1.z + acc[7][r] * ad1.w;
    s += __shfl_xor(s, 1);
    d += __shfl_xor(d, 1);
    if (ok && (rlo & 1) == 0) {
      asn[row * 8 + (rlo >> 1)] = s;
      adn[row * 8 + (rlo >> 1)] = d;
    }
  }
}

// ---- FUSED fine-CSR + layer-1 gather: one block per 128-node bucket ---------
__global__ __launch_bounds__(512) void csr_gather1_kernel(
    const int* __restrict__ staging, const int* __restrict__ bucket_base,
    int* __restrict__ rp, int* __restrict__ col,
    const float* __restrict__ asn, const float* __restrict__ adn,
    const uint4* __restrict__ h8, const float* __restrict__ b1,
    ushort_t* __restrict__ x2) {
  __shared__ int degL[BKN];
  __shared__ int curL[BKN];
  __shared__ int startL[BKN + 1];
  __shared__ int sdata[2][BKN];
  int bk = blockIdx.x, t = threadIdx.x;
  int ebase = bucket_base[bk], eend = bucket_base[bk + 1];
  int ecnt = eend - ebase;
  if (t < BKN) degL[t] = 0;
  __syncthreads();
  for (int e = t; e < ecnt; e += 512)
    atomicAdd(&degL[staging[ebase + e] >> 17], 1);
  __syncthreads();
  if (t < BKN) sdata[0][t] = degL[t];
  __syncthreads();
  int sp = 0;
  for (int off = 1; off < BKN; off <<= 1) {
    if (t < BKN) {
      int val = sdata[sp][t];
      if (t >= off) val += sdata[sp][t - off];
      sdata[sp ^ 1][t] = val;
    }
    __syncthreads();
    sp ^= 1;
  }
  if (t < BKN) {
    int ex = sdata[sp][t] - degL[t];  // exclusive
    curL[t] = ex;
    startL[t] = ebase + ex;
    int node = bk * BKN + t;
    if (node < NN) rp[node] = ebase + ex;
  }
  if (t == 0) startL[BKN] = eend;
  if (bk == 0 && t == 0) rp[NN] = EN;
  __syncthreads();
  for (int e = t; e < ecnt; e += 512) {
    int pk = staging[ebase + e];
    int pos = atomicAdd(&curL[pk >> 17], 1);
    col[ebase + pos] = pk & 0x1FFFF;
  }
  __syncthreads();
  // ---- phase 2: gather1 (8 lanes/node, lane = head); 64 nodes per pass ----
  int g = t >> 3, lane = t & 7;
#pragma unroll
  for (int pass = 0; pass < 2; ++pass) {
    int i = pass * 64 + g;
    int node = bk * BKN + i;
    if (node >= NN) continue;
    float aD = adn[node * 8 + lane];
    int p = startL[i], p1 = startL[i + 1];
    float a[16];
#pragma unroll
    for (int j = 0; j < 16; ++j) a[j] = 0.f;
    float den = 0.f;
    for (; p + 1 < p1; p += 2) {
      int s0 = col[p], s1 = col[p + 1];
      float e0 = asn[s0 * 8 + lane] + aD;
      float e1 = asn[s1 * 8 + lane] + aD;
      uint4 q0 = h8[(size_t)s0 * 8 + lane];
      uint4 q1 = h8[(size_t)s1 * 8 + lane];
      e0 = e0 > 0.f ? e0 : NEG * e0;
      e1 = e1 > 0.f ? e1 : NEG * e1;
      float ee0 = __expf(e0), ee1 = __expf(e1);
      float d0[4], d1[4], d2[4], d3[4];
      fp8_unpack4(q0.x, d0); fp8_unpack4(q0.y, d1);
      fp8_unpack4(q0.z, d2); fp8_unpack4(q0.w, d3);
      float g0[4], g1[4], g2[4], g3[4];
      fp8_unpack4(q1.x, g0); fp8_unpack4(q1.y, g1);
      fp8_unpack4(q1.z, g2); fp8_unpack4(q1.w, g3);
#pragma unroll
      for (int j = 0; j < 4; ++j) {
        a[j]      += ee0 * d0[j] + ee1 * g0[j];
        a[4 + j]  += ee0 * d1[j] + ee1 * g1[j];
        a[8 + j]  += ee0 * d2[j] + ee1 * g2[j];
        a[12 + j] += ee0 * d3[j] + ee1 * g3[j];
      }
      den += ee0 + ee1;
    }
    if (p < p1) {
      int s0 = col[p];
      float e0 = asn[s0 * 8 + lane] + aD;
      uint4 q0 = h8[(size_t)s0 * 8 + lane];
      e0 = e0 > 0.f ? e0 : NEG * e0;
      float ee0 = __expf(e0);
      float d0[4], d1[4], d2[4], d3[4];
      fp8_unpack4(q0.x, d0); fp8_unpack4(q0.y, d1);
      fp8_unpack4(q0.z, d2); fp8_unpack4(q0.w, d3);
#pragma unroll
      for (int j = 0; j < 4; ++j) {
        a[j] += ee0 * d0[j];
        a[4 + j] += ee0 * d1[j];
        a[8 + j] += ee0 * d2[j];
        a[12 + j] += ee0 * d3[j];
      }
      den += ee0;
    }
    float inv = 1.f / den;
    const float4* b4 = (const float4*)b1;  // channels 16*lane + 0..15
    U8 t0, t1;
#pragma unroll
    for (int h = 0; h < 4; ++h) {
      float4 bv = b4[lane * 4 + h];
      float o0 = fmaf(a[h * 4 + 0], inv, bv.x);
      float o1 = fmaf(a[h * 4 + 1], inv, bv.y);
      float o2 = fmaf(a[h * 4 + 2], inv, bv.z);
      float o3 = fmaf(a[h * 4 + 3], inv, bv.w);
      o0 = o0 > 0.f ? o0 : __expf(o0) - 1.f;
      o1 = o1 > 0.f ? o1 : __expf(o1) - 1.f;
      o2 = o2 > 0.f ? o2 : __expf(o2) - 1.f;
      o3 = o3 > 0.f ? o3 : __expf(o3) - 1.f;
      U8& tt = (h < 2) ? t0 : t1;
      int base = (h & 1) * 4;
      tt.u[base + 0] = f2bf(o0); tt.u[base + 1] = f2bf(o1);
      tt.u[base + 2] = f2bf(o2); tt.u[base + 3] = f2bf(o3);
    }
    uint4* xr = (uint4*)(x2 + (size_t)node * F1);  // row = 8 uint4
    xr[lane * 2 + 0] = t0.q;
    xr[lane * 2 + 1] = t1.q;
  }
}

// ---------- MFMA GEMM2 (fused layer-2 prep; no LDS, B from WT2) --------------
__global__ __launch_bounds__(256) void mfma_gemm2_kernel(
    const ushort_t* __restrict__ X2, const ushort_t* __restrict__ WT2,
    const float* __restrict__ a_src, const float* __restrict__ a_dst,
    uint_t* __restrict__ h28, float* __restrict__ asn, float* __restrict__ adn,
    int nrows) {
  const int tid = threadIdx.x;
  const int wave = tid >> 6, lane = tid & 63;
  const int row0 = blockIdx.x * 64 + wave * 16;
  const int rlo = lane & 15, khi = lane >> 4;

  f32x4 acc[4];
#pragma unroll
  for (int n = 0; n < 4; ++n) acc[n] = (f32x4){0.f, 0.f, 0.f, 0.f};

#pragma unroll
  for (int ks = 0; ks < 4; ++ks) {
    const int kk = ks * 32 + khi * 8;
    int row = row0 + rlo;
    if (row >= nrows) row = nrows - 1;
    U8 t;
    t.q = *(const uint4*)(X2 + (size_t)row * 128 + kk);
    short8v a = t.v;
#pragma unroll
    for (int nf = 0; nf < 4; ++nf) {
      short8v b = *(const short8v*)(WT2 + (nf * 16 + rlo) * 128 + kk);
      acc[nf] = __builtin_amdgcn_mfma_f32_16x16x32_bf16(a, b, acc[nf], 0, 0, 0);
    }
  }
  float4 as = ((const float4*)a_src)[rlo];
  float4 ad = ((const float4*)a_dst)[rlo];
  int rbase = row0 + khi * 4;
#pragma unroll
  for (int r = 0; r < 4; ++r) {
    int row = rbase + r;
    bool ok = (row < nrows);
    uint_t pk = fp8_pack4(acc[0][r], acc[1][r], acc[2][r], acc[3][r]);
    if (ok) h28[(size_t)row * 16 + rlo] = pk;
    float s = acc[0][r] * as.x + acc[1][r] * as.y +
              acc[2][r] * as.z + acc[3][r] * as.w;
    float d = acc[0][r] * ad.x + acc[1][r] * ad.y +
              acc[2][r] * ad.z + acc[3][r] * ad.w;
    s += __shfl_xor(s, 1); s += __shfl_xor(s, 2);
    s += __shfl_xor(s, 4); s += __shfl_xor(s, 8);
    d += __shfl_xor(d, 1); d += __shfl_xor(d, 2);
    d += __shfl_xor(d, 4); d += __shfl_xor(d, 8);
    if (ok && rlo == 0) { asn[row] = s; adn[row] = d; }
  }
}

// ------ layer-2 gather: 8 lanes/node, 2-edge unroll + log_softmax ------------
__global__ __launch_bounds__(256) void gather2_kernel(
    const int* __restrict__ rp, const int* __restrict__ col,
    const float* __restrict__ asn, const float* __restrict__ adn,
    const uint2* __restrict__ h28, const float* __restrict__ b2,
    float* __restrict__ out) {
  int node = (blockIdx.x << 5) + (threadIdx.x >> 3);
  if (node >= NN) return;
  int lane = threadIdx.x & 7;
  float aD = adn[node];
  int p = rp[node], p1 = rp[node + 1];
  float a[8];
#pragma unroll
  for (int j = 0; j < 8; ++j) a[j] = 0.f;
  float den = 0.f;

  for (; p + 1 < p1; p += 2) {
    int s0 = col[p], s1 = col[p + 1];
    float e0 = asn[s0] + aD;
    float e1 = asn[s1] + aD;
    uint2 q0 = h28[(size_t)s0 * 8 + lane];
    uint2 q1 = h28[(size_t)s1 * 8 + lane];
    e0 = e0 > 0.f ? e0 : NEG * e0;
    e1 = e1 > 0.f ? e1 : NEG * e1;
    float ee0 = __expf(e0), ee1 = __expf(e1);
    float d0[4], d1[4], g0[4], g1[4];
    fp8_unpack4(q0.x, d0); fp8_unpack4(q0.y, d1);
    fp8_unpack4(q1.x, g0); fp8_unpack4(q1.y, g1);
#pragma unroll
    for (int j = 0; j < 4; ++j) {
      a[j] += ee0 * d0[j] + ee1 * g0[j];
      a[4 + j] += ee0 * d1[j] + ee1 * g1[j];
    }
    den += ee0 + ee1;
  }
  if (p < p1) {
    int s0 = col[p];
    float e0 = asn[s0] + aD;
    uint2 q0 = h28[(size_t)s0 * 8 + lane];
    e0 = e0 > 0.f ? e0 : NEG * e0;
    float ee0 = __expf(e0);
    float d0[4], d1[4];
    fp8_unpack4(q0.x, d0); fp8_unpack4(q0.y, d1);
#pragma unroll
    for (int j = 0; j < 4; ++j) {
      a[j] += ee0 * d0[j];
      a[4 + j] += ee0 * d1[j];
    }
    den += ee0;
  }
  float inv = 1.f / den;
  float4 bv0 = ((const float4*)b2)[lane * 2 + 0];
  float4 bv1 = ((const float4*)b2)[lane * 2 + 1];
  float v[8];
  v[0] = fmaf(a[0], inv, bv0.x); v[1] = fmaf(a[1], inv, bv0.y);
  v[2] = fmaf(a[2], inv, bv0.z); v[3] = fmaf(a[3], inv, bv0.w);
  v[4] = fmaf(a[4], inv, bv1.x); v[5] = fmaf(a[5], inv, bv1.y);
  v[6] = fmaf(a[6], inv, bv1.z); v[7] = fmaf(a[7], inv, bv1.w);
  float m = v[0];
#pragma unroll
  for (int j = 1; j < 8; ++j) m = fmaxf(m, v[j]);
#pragma unroll
  for (int k = 1; k < 8; k <<= 1) m = fmaxf(m, __shfl_xor(m, k));
  float ex = 0.f;
#pragma unroll
  for (int j = 0; j < 8; ++j) ex += __expf(v[j] - m);
#pragma unroll
  for (int k = 1; k < 8; k <<= 1) ex += __shfl_xor(ex, k);
  float lse = m + __logf(ex);
  float4 r0 = {v[0] - lse, v[1] - lse, v[2] - lse, v[3] - lse};
  float4 r1 = {v[4] - lse, v[5] - lse, v[6] - lse, v[7] - lse};
  float4* orow = (float4*)(out + (size_t)node * NC);
  orow[lane * 2 + 0] = r0;
  orow[lane * 2 + 1] = r1;
}

extern "C" void kernel_launch(void* const* d_in, const int* in_sizes, int n_in,
                              void* d_out, int out_size, void* d_ws,
                              size_t ws_size, hipStream_t stream) {
  const float* x = (const float*)d_in[0];
  const int* edge_index = (const int*)d_in[1];
  const float* W1 = (const float*)d_in[2];
  const float* a_src1 = (const float*)d_in[3];
  const float* a_dst1 = (const float*)d_in[4];
  const float* b1 = (const float*)d_in[5];
  const float* W2 = (const float*)d_in[6];
  const float* a_src2 = (const float*)d_in[7];
  const float* a_dst2 = (const float*)d_in[8];
  const float* b2 = (const float*)d_in[9];
  float* out = (float*)d_out;
  float* ws = (float*)d_ws;

  // workspace layout (float offsets), non-overlapping:
  ushort_t* x2b = (ushort_t*)ws;               // [0, 6.4M)   bf16 x2
  uint4* h8 = (uint4*)(ws + 6400000);          // [6.4M, 9.6M)  fp8 h1 (linear)
  uint2* h28 = (uint2*)(ws + 9600000);         // [9.6M, 11.2M) fp8 h2 (linear)
  float* asn1 = ws + 11200000;                 // [11.2M, 12.0M)
  float* adn1 = ws + 12000000;                 // [12.0M, 12.8M)
  float* asn2 = ws + 12800000;                 // [12.8M, 12.9M)
  float* adn2 = ws + 12900000;                 // [12.9M, 13.0M)
  ushort_t* WT1 = (ushort_t*)(ws + 13000000);  // 16384 bf16
  ushort_t* WT2 = (ushort_t*)(ws + 13010000);  // 8192 bf16
  int* rp = (int*)(ws + 13020000);             // NN+1
  int* col = rp + NN + 1;                      // EN
  int* staging = col + EN;                     // EN
  int* cnt = staging + EN;                     // NBUK*NBLK = 200192
  int* bucket_base = cnt + NBUK * NBLK;        // NBUK+1
  int* colsum = bucket_base + NBUK + 1;        // NBUK   (~17.0M floats)

  const int* srcA = edge_index;
  const int* dstA = edge_index + NE;

  // ---- CSR P1 (fused wt_prep) + parallel 2-level scan ----
  bucket_count_kernel<<<NBLK, 512, 0, stream>>>(dstA, cnt, W1, W2, WT1, WT2);
  scan_chunks_kernel<<<NBUK, 256, 0, stream>>>(cnt, colsum);
  scan_buckets_kernel<<<1, 1024, 0, stream>>>(colsum, bucket_base);
  // ---- scatter || gemm1 (horizontal fusion) ----
  scatter_gemm1_kernel<<<NBLK + (NN + 127) / 128, 512, 0, stream>>>(
      srcA, dstA, cnt, bucket_base, staging, x, WT1, a_src1, a_dst1,
      (uint2*)h8, asn1, adn1, NN);
  // ---- fused fine-CSR + layer-1 gather (one block per 128-node bucket) ----
  csr_gather1_kernel<<<NBUK, 512, 0, stream>>>(staging, bucket_base, rp, col,
                                               asn1, adn1, h8, b1, x2b);
  // ---- layer 2 ----
  mfma_gemm2_kernel<<<(NN + 63) / 64, 256, 0, stream>>>(
      x2b, WT2, a_src2, a_dst2, (uint_t*)h28, asn2, adn2, NN);
  gather2_kernel<<<(NN + 31) / 32, 256, 0, stream>>>(rp, col, asn2, adn2, h28,
                                                     b2, out);
}

// Round 21
// 188.992 us; speedup vs baseline: 1.7321x; 1.0405x over previous
//
#include <hip/hip_runtime.h>

#define NN 100000
#define NE 1600000
#define EN (NE + NN)          // edges incl. self-loops
#define FIN 128
#define H1 8
#define C1 16
#define F1 128                // H1*C1
#define NC 64
#define NEG 0.2f

// ---- CSR-build multisplit parameters ----
#define BSH 7                 // bucket = dst >> BSH
#define BKN 128               // nodes per bucket
#define NBUK ((NN + BKN - 1) / BKN)   // 782
#define NBLK 256              // edge-chunk blocks for P1/P2
#define CHUNK ((EN + NBLK - 1) / NBLK) // 6641
// XCD-aware chunk swizzle (kept from r17; neutral but harmless)
__device__ __forceinline__ int chunk_of_block(int b) {
  return (b & 7) * (NBLK / 8) + (b >> 3);
}

typedef unsigned short ushort_t;
typedef unsigned int uint_t;
typedef __attribute__((ext_vector_type(8))) short short8v;
typedef __attribute__((ext_vector_type(4))) float f32x4;
typedef __attribute__((ext_vector_type(2))) float f32x2;

union U8 { ushort_t u[8]; short8v v; uint4 q; };

__device__ __forceinline__ ushort_t f2bf(float f) {
  uint_t u = __builtin_bit_cast(uint_t, f);
  u += 0x7FFF + ((u >> 16) & 1);  // RNE
  return (ushort_t)(u >> 16);
}
__device__ __forceinline__ float bflo(uint_t u) {
  return __builtin_bit_cast(float, u << 16);
}
__device__ __forceinline__ float bfhi(uint_t u) {
  return __builtin_bit_cast(float, u & 0xFFFF0000u);
}

// ---------------- fp8 encode/decode (HW cvt preferred) -----------------------
#if __has_builtin(__builtin_amdgcn_cvt_pk_fp8_f32) && \
    __has_builtin(__builtin_amdgcn_cvt_pk_f32_fp8)
__device__ __forceinline__ uint_t fp8_pack4(float f0, float f1, float f2,
                                            float f3) {
  int p = 0;
  p = __builtin_amdgcn_cvt_pk_fp8_f32(f0, f1, p, false);
  p = __builtin_amdgcn_cvt_pk_fp8_f32(f2, f3, p, true);
  return (uint_t)p;
}
__device__ __forceinline__ void fp8_unpack4(uint_t w, float* o) {
  f32x2 d0 = __builtin_amdgcn_cvt_pk_f32_fp8((int)w, false);
  f32x2 d1 = __builtin_amdgcn_cvt_pk_f32_fp8((int)w, true);
  o[0] = d0.x; o[1] = d0.y; o[2] = d1.x; o[3] = d1.y;
}
#else
__device__ __forceinline__ uint_t fp8_enc1(float f) {
  uint_t u = __builtin_bit_cast(uint_t, f);
  uint_t s = (u >> 24) & 0x80u;
  int e = (int)((u >> 23) & 0xFF) - 127;
  if (e < -9) return s;
  if (e < -6) {
    float af = __builtin_bit_cast(float, u & 0x7FFFFFFFu);
    uint_t m = (uint_t)(af * 512.f + 0.5f);
    return s | m;
  }
  uint_t mant = u & 0x7FFFFF;
  uint_t keep = mant >> 20;
  uint_t rest = mant & 0xFFFFF;
  keep += (rest > 0x80000u) || (rest == 0x80000u && (keep & 1));
  uint_t ee = (uint_t)(e + 7);
  if (keep == 8) { keep = 0; ee += 1; }
  if (ee > 15 || (ee == 15 && keep > 6)) return s | 0x7E;
  return s | (ee << 3) | keep;
}
__device__ __forceinline__ float fp8_dec1(uint_t b) {
  uint_t s = (b & 0x80u) << 24;
  uint_t e = (b >> 3) & 15u, m = b & 7u;
  if (e == 0) {
    float v = (float)m * (1.0f / 512.0f);
    return __builtin_bit_cast(float, s | __builtin_bit_cast(uint_t, v));
  }
  return __builtin_bit_cast(float, s | ((e + 120u) << 23) | (m << 20));
}
__device__ __forceinline__ uint_t fp8_pack4(float f0, float f1, float f2,
                                            float f3) {
  return fp8_enc1(f0) | (fp8_enc1(f1) << 8) | (fp8_enc1(f2) << 16) |
         (fp8_enc1(f3) << 24);
}
__device__ __forceinline__ void fp8_unpack4(uint_t w, float* o) {
  o[0] = fp8_dec1(w & 0xFF); o[1] = fp8_dec1((w >> 8) & 0xFF);
  o[2] = fp8_dec1((w >> 16) & 0xFF); o[3] = fp8_dec1(w >> 24);
}
#endif

// ------------------ CSR P1: count (fused weight prep) ------------------------
__global__ __launch_bounds__(512) void bucket_count_kernel(
    const int* __restrict__ dstA, int* __restrict__ cnt,
    const float* __restrict__ W1, const float* __restrict__ W2,
    ushort_t* __restrict__ WT1, ushort_t* __restrict__ WT2) {
  __shared__ int histL[NBUK];
  int b = blockIdx.x, t = threadIdx.x;
  int gid = b * 512 + t;
  if (gid < 128 * 128) {
    int n = gid >> 7, k = gid & 127;
    int c = (n & 15) * 8 + (n >> 4);
    WT1[gid] = f2bf(W1[k * 128 + c]);
  } else if (gid < 128 * 128 + 64 * 128) {
    int j = gid - 128 * 128;
    int n = j >> 7, k = j & 127;
    int c = (n & 15) * 4 + (n >> 4);
    WT2[j] = f2bf(W2[k * 64 + c]);
  }
  for (int i = t; i < NBUK; i += 512) histL[i] = 0;
  __syncthreads();
  int ch = chunk_of_block(b);
  int e0 = ch * CHUNK, e1 = min(e0 + CHUNK, EN);
  for (int e = e0 + t; e < e1; e += 512) {
    int d = (e < NE) ? dstA[e] : (e - NE);
    atomicAdd(&histL[d >> BSH], 1);
  }
  __syncthreads();
  for (int i = t; i < NBUK; i += 512) cnt[i * NBLK + ch] = histL[i];
}

// scan A: per-bucket 256-wide LDS scan over chunks (in place), emit colsum.
__global__ __launch_bounds__(256) void scan_chunks_kernel(
    int* __restrict__ cnt, int* __restrict__ colsum) {
  __shared__ int sd[2][256];
  int j = blockIdx.x, t = threadIdx.x;
  int v = cnt[j * NBLK + t];
  sd[0][t] = v;
  __syncthreads();
  int sp = 0;
  for (int off = 1; off < 256; off <<= 1) {
    int val = sd[sp][t];
    if (t >= off) val += sd[sp][t - off];
    sd[sp ^ 1][t] = val;
    __syncthreads();
    sp ^= 1;
  }
  cnt[j * NBLK + t] = sd[sp][t] - v;  // exclusive within bucket
  if (t == 255) colsum[j] = sd[sp][255];
}

// scan B: one block scans the NBUK colsums into bucket_base (NBUK <= 1024).
__global__ __launch_bounds__(1024) void scan_buckets_kernel(
    const int* __restrict__ colsum, int* __restrict__ bucket_base) {
  __shared__ int sd[2][1024];
  int t = threadIdx.x;
  int v = (t < NBUK) ? colsum[t] : 0;
  sd[0][t] = v;
  __syncthreads();
  int sp = 0;
  for (int off = 1; off < 1024; off <<= 1) {
    int val = sd[sp][t];
    if (t >= off) val += sd[sp][t - off];
    sd[sp ^ 1][t] = val;
    __syncthreads();
    sp ^= 1;
  }
  if (t < NBUK) bucket_base[t] = sd[sp][t] - v;
  if (t == 0) bucket_base[NBUK] = EN;
}

// ---- HORIZONTAL FUSION: blocks [0,NBLK) scatter edges; rest run gemm1 -------
// cursor = within-bucket exclusive (cnt) + bucket_base (added on load).
__global__ __launch_bounds__(512) void scatter_gemm1_kernel(
    const int* __restrict__ srcA, const int* __restrict__ dstA,
    const int* __restrict__ cnt, const int* __restrict__ bucket_base,
    int* __restrict__ staging,
    const float* __restrict__ X, const ushort_t* __restrict__ WT1,
    const float* __restrict__ a_src, const float* __restrict__ a_dst,
    uint2* __restrict__ h8, float* __restrict__ asn, float* __restrict__ adn,
    int nrows) {
  __shared__ int cur[NBUK];
  if (blockIdx.x < NBLK) {
    int b = blockIdx.x, t = threadIdx.x;
    int ch = chunk_of_block(b);
    for (int i = t; i < NBUK; i += 512)
      cur[i] = cnt[i * NBLK + ch] + bucket_base[i];
    __syncthreads();
    int e0 = ch * CHUNK, e1 = min(e0 + CHUNK, EN);
    for (int e = e0 + t; e < e1; e += 512) {
      int s, d;
      if (e < NE) { s = srcA[e]; d = dstA[e]; } else { s = e - NE; d = s; }
      int pos = atomicAdd(&cur[d >> BSH], 1);
      staging[pos] = s | ((d & (BKN - 1)) << 17);
    }
    return;
  }
  // ---------------- MFMA GEMM1 (fused layer-1 prep) ----------------
  const int tid = threadIdx.x;
  const int wave = tid >> 6, lane = tid & 63;
  const int row0 = (blockIdx.x - NBLK) * 128 + wave * 16;
  const int rlo = lane & 15, khi = lane >> 4;  // khi in 0..3

  f32x4 acc[8];
#pragma unroll
  for (int n = 0; n < 8; ++n) acc[n] = (f32x4){0.f, 0.f, 0.f, 0.f};

#pragma unroll
  for (int ks = 0; ks < 4; ++ks) {
    const int kk = ks * 32 + khi * 8;
    int row = row0 + rlo;
    if (row >= nrows) row = nrows - 1;
    const float4* xp = (const float4*)(X + (size_t)row * 128 + kk);
    float4 u = xp[0], v = xp[1];
    U8 t;
    t.u[0] = f2bf(u.x); t.u[1] = f2bf(u.y); t.u[2] = f2bf(u.z); t.u[3] = f2bf(u.w);
    t.u[4] = f2bf(v.x); t.u[5] = f2bf(v.y); t.u[6] = f2bf(v.z); t.u[7] = f2bf(v.w);
    short8v a = t.v;
#pragma unroll
    for (int nf = 0; nf < 8; ++nf) {
      short8v b = *(const short8v*)(WT1 + (nf * 16 + rlo) * 128 + kk);
      acc[nf] = __builtin_amdgcn_mfma_f32_16x16x32_bf16(a, b, acc[nf], 0, 0, 0);
    }
  }
  const float4* as4 = (const float4*)a_src;
  const float4* ad4 = (const float4*)a_dst;
  float4 as0 = as4[rlo * 2], as1 = as4[rlo * 2 + 1];
  float4 ad0 = ad4[rlo * 2], ad1 = ad4[rlo * 2 + 1];
  // C/D layout: col = lane&15, row = (lane>>4)*4 + reg  [m89-verified]
  int rbase = row0 + khi * 4;
#pragma unroll
  for (int r = 0; r < 4; ++r) {
    int row = rbase + r;
    bool ok = (row < nrows);
    uint2 pk;
    pk.x = fp8_pack4(acc[0][r], acc[1][r], acc[2][r], acc[3][r]);
    pk.y = fp8_pack4(acc[4][r], acc[5][r], acc[6][r], acc[7][r]);
    if (ok) h8[(size_t)row * 16 + rlo] = pk;
    float s = acc[0][r] * as0.x + acc[1][r] * as0.y +
              acc[2][r] * as0.z + acc[3][r] * as0.w +
              acc[4][r] * as1.x + acc[5][r] * as1.y +
              acc[6][r] * as1.z + acc[7][r] * as1.w;
    float d = acc[0][r] * ad0.x + acc[1][r] * ad0.y +
              acc[2][r] * ad0.z + acc[3][r] * ad0.w +
              acc[4][r] * ad1.x + acc[5][r] * ad1.y +
              acc[6][r] * ad1.z + acc[7][r] * ad1.w;
    s += __shfl_xor(s, 1);
    d += __shfl_xor(d, 1);
    if (ok && (rlo & 1) == 0) {
      asn[row * 8 + (rlo >> 1)] = s;
      adn[row * 8 + (rlo >> 1)] = d;
    }
  }
}

// ---- FUSED fine-CSR + layer-1 gather: 1024 threads, one pass (128 nodes) ----
__global__ __launch_bounds__(1024) void csr_gather1_kernel(
    const int* __restrict__ staging, const int* __restrict__ bucket_base,
    int* __restrict__ rp, int* __restrict__ col,
    const float* __restrict__ asn, const float* __restrict__ adn,
    const uint4* __restrict__ h8, const float* __restrict__ b1,
    ushort_t* __restrict__ x2) {
  __shared__ int degL[BKN];
  __shared__ int curL[BKN];
  __shared__ int startL[BKN + 1];
  __shared__ int sdata[2][BKN];
  int bk = blockIdx.x, t = threadIdx.x;
  int ebase = bucket_base[bk], eend = bucket_base[bk + 1];
  int ecnt = eend - ebase;
  if (t < BKN) degL[t] = 0;
  __syncthreads();
  for (int e = t; e < ecnt; e += 1024)
    atomicAdd(&degL[staging[ebase + e] >> 17], 1);
  __syncthreads();
  if (t < BKN) sdata[0][t] = degL[t];
  __syncthreads();
  int sp = 0;
  for (int off = 1; off < BKN; off <<= 1) {
    if (t < BKN) {
      int val = sdata[sp][t];
      if (t >= off) val += sdata[sp][t - off];
      sdata[sp ^ 1][t] = val;
    }
    __syncthreads();
    sp ^= 1;
  }
  if (t < BKN) {
    int ex = sdata[sp][t] - degL[t];  // exclusive
    curL[t] = ex;
    startL[t] = ebase + ex;
    int node = bk * BKN + t;
    if (node < NN) rp[node] = ebase + ex;
  }
  if (t == 0) startL[BKN] = eend;
  if (bk == 0 && t == 0) rp[NN] = EN;
  __syncthreads();
  for (int e = t; e < ecnt; e += 1024) {
    int pk = staging[ebase + e];
    int pos = atomicAdd(&curL[pk >> 17], 1);
    col[ebase + pos] = pk & 0x1FFFF;
  }
  __syncthreads();
  // ---- phase 2: gather1 (8 lanes/node, lane = head); all 128 nodes, 1 pass --
  int i = t >> 3, lane = t & 7;
  int node = bk * BKN + i;
  if (node >= NN) return;
  float aD = adn[node * 8 + lane];
  int p = startL[i], p1 = startL[i + 1];
  float a[16];
#pragma unroll
  for (int j = 0; j < 16; ++j) a[j] = 0.f;
  float den = 0.f;
  for (; p + 1 < p1; p += 2) {
    int s0 = col[p], s1 = col[p + 1];
    float e0 = asn[s0 * 8 + lane] + aD;
    float e1 = asn[s1 * 8 + lane] + aD;
    uint4 q0 = h8[(size_t)s0 * 8 + lane];
    uint4 q1 = h8[(size_t)s1 * 8 + lane];
    e0 = e0 > 0.f ? e0 : NEG * e0;
    e1 = e1 > 0.f ? e1 : NEG * e1;
    float ee0 = __expf(e0), ee1 = __expf(e1);
    float d0[4], d1[4], d2[4], d3[4];
    fp8_unpack4(q0.x, d0); fp8_unpack4(q0.y, d1);
    fp8_unpack4(q0.z, d2); fp8_unpack4(q0.w, d3);
    float g0[4], g1[4], g2[4], g3[4];
    fp8_unpack4(q1.x, g0); fp8_unpack4(q1.y, g1);
    fp8_unpack4(q1.z, g2); fp8_unpack4(q1.w, g3);
#pragma unroll
    for (int j = 0; j < 4; ++j) {
      a[j]      += ee0 * d0[j] + ee1 * g0[j];
      a[4 + j]  += ee0 * d1[j] + ee1 * g1[j];
      a[8 + j]  += ee0 * d2[j] + ee1 * g2[j];
      a[12 + j] += ee0 * d3[j] + ee1 * g3[j];
    }
    den += ee0 + ee1;
  }
  if (p < p1) {
    int s0 = col[p];
    float e0 = asn[s0 * 8 + lane] + aD;
    uint4 q0 = h8[(size_t)s0 * 8 + lane];
    e0 = e0 > 0.f ? e0 : NEG * e0;
    float ee0 = __expf(e0);
    float d0[4], d1[4], d2[4], d3[4];
    fp8_unpack4(q0.x, d0); fp8_unpack4(q0.y, d1);
    fp8_unpack4(q0.z, d2); fp8_unpack4(q0.w, d3);
#pragma unroll
    for (int j = 0; j < 4; ++j) {
      a[j] += ee0 * d0[j];
      a[4 + j] += ee0 * d1[j];
      a[8 + j] += ee0 * d2[j];
      a[12 + j] += ee0 * d3[j];
    }
    den += ee0;
  }
  float inv = 1.f / den;
  const float4* b4 = (const float4*)b1;  // channels 16*lane + 0..15
  U8 t0, t1;
#pragma unroll
  for (int h = 0; h < 4; ++h) {
    float4 bv = b4[lane * 4 + h];
    float o0 = fmaf(a[h * 4 + 0], inv, bv.x);
    float o1 = fmaf(a[h * 4 + 1], inv, bv.y);
    float o2 = fmaf(a[h * 4 + 2], inv, bv.z);
    float o3 = fmaf(a[h * 4 + 3], inv, bv.w);
    o0 = o0 > 0.f ? o0 : __expf(o0) - 1.f;
    o1 = o1 > 0.f ? o1 : __expf(o1) - 1.f;
    o2 = o2 > 0.f ? o2 : __expf(o2) - 1.f;
    o3 = o3 > 0.f ? o3 : __expf(o3) - 1.f;
    U8& tt = (h < 2) ? t0 : t1;
    int base = (h & 1) * 4;
    tt.u[base + 0] = f2bf(o0); tt.u[base + 1] = f2bf(o1);
    tt.u[base + 2] = f2bf(o2); tt.u[base + 3] = f2bf(o3);
  }
  uint4* xr = (uint4*)(x2 + (size_t)node * F1);  // row = 8 uint4
  xr[lane * 2 + 0] = t0.q;
  xr[lane * 2 + 1] = t1.q;
}

// ---------- MFMA GEMM2 (fused layer-2 prep; no LDS, B from WT2) --------------
__global__ __launch_bounds__(256) void mfma_gemm2_kernel(
    const ushort_t* __restrict__ X2, const ushort_t* __restrict__ WT2,
    const float* __restrict__ a_src, const float* __restrict__ a_dst,
    uint_t* __restrict__ h28, float* __restrict__ asn, float* __restrict__ adn,
    int nrows) {
  const int tid = threadIdx.x;
  const int wave = tid >> 6, lane = tid & 63;
  const int row0 = blockIdx.x * 64 + wave * 16;
  const int rlo = lane & 15, khi = lane >> 4;

  f32x4 acc[4];
#pragma unroll
  for (int n = 0; n < 4; ++n) acc[n] = (f32x4){0.f, 0.f, 0.f, 0.f};

#pragma unroll
  for (int ks = 0; ks < 4; ++ks) {
    const int kk = ks * 32 + khi * 8;
    int row = row0 + rlo;
    if (row >= nrows) row = nrows - 1;
    U8 t;
    t.q = *(const uint4*)(X2 + (size_t)row * 128 + kk);
    short8v a = t.v;
#pragma unroll
    for (int nf = 0; nf < 4; ++nf) {
      short8v b = *(const short8v*)(WT2 + (nf * 16 + rlo) * 128 + kk);
      acc[nf] = __builtin_amdgcn_mfma_f32_16x16x32_bf16(a, b, acc[nf], 0, 0, 0);
    }
  }
  float4 as = ((const float4*)a_src)[rlo];
  float4 ad = ((const float4*)a_dst)[rlo];
  int rbase = row0 + khi * 4;
#pragma unroll
  for (int r = 0; r < 4; ++r) {
    int row = rbase + r;
    bool ok = (row < nrows);
    uint_t pk = fp8_pack4(acc[0][r], acc[1][r], acc[2][r], acc[3][r]);
    if (ok) h28[(size_t)row * 16 + rlo] = pk;
    float s = acc[0][r] * as.x + acc[1][r] * as.y +
              acc[2][r] * as.z + acc[3][r] * as.w;
    float d = acc[0][r] * ad.x + acc[1][r] * ad.y +
              acc[2][r] * ad.z + acc[3][r] * ad.w;
    s += __shfl_xor(s, 1); s += __shfl_xor(s, 2);
    s += __shfl_xor(s, 4); s += __shfl_xor(s, 8);
    d += __shfl_xor(d, 1); d += __shfl_xor(d, 2);
    d += __shfl_xor(d, 4); d += __shfl_xor(d, 8);
    if (ok && rlo == 0) { asn[row] = s; adn[row] = d; }
  }
}

// ------ layer-2 gather: 8 lanes/node, 2-edge unroll + log_softmax ------------
__global__ __launch_bounds__(256) void gather2_kernel(
    const int* __restrict__ rp, const int* __restrict__ col,
    const float* __restrict__ asn, const float* __restrict__ adn,
    const uint2* __restrict__ h28, const float* __restrict__ b2,
    float* __restrict__ out) {
  int node = (blockIdx.x << 5) + (threadIdx.x >> 3);
  if (node >= NN) return;
  int lane = threadIdx.x & 7;
  float aD = adn[node];
  int p = rp[node], p1 = rp[node + 1];
  float a[8];
#pragma unroll
  for (int j = 0; j < 8; ++j) a[j] = 0.f;
  float den = 0.f;

  for (; p + 1 < p1; p += 2) {
    int s0 = col[p], s1 = col[p + 1];
    float e0 = asn[s0] + aD;
    float e1 = asn[s1] + aD;
    uint2 q0 = h28[(size_t)s0 * 8 + lane];
    uint2 q1 = h28[(size_t)s1 * 8 + lane];
    e0 = e0 > 0.f ? e0 : NEG * e0;
    e1 = e1 > 0.f ? e1 : NEG * e1;
    float ee0 = __expf(e0), ee1 = __expf(e1);
    float d0[4], d1[4], g0[4], g1[4];
    fp8_unpack4(q0.x, d0); fp8_unpack4(q0.y, d1);
    fp8_unpack4(q1.x, g0); fp8_unpack4(q1.y, g1);
#pragma unroll
    for (int j = 0; j < 4; ++j) {
      a[j] += ee0 * d0[j] + ee1 * g0[j];
      a[4 + j] += ee0 * d1[j] + ee1 * g1[j];
    }
    den += ee0 + ee1;
  }
  if (p < p1) {
    int s0 = col[p];
    float e0 = asn[s0] + aD;
    uint2 q0 = h28[(size_t)s0 * 8 + lane];
    e0 = e0 > 0.f ? e0 : NEG * e0;
    float ee0 = __expf(e0);
    float d0[4], d1[4];
    fp8_unpack4(q0.x, d0); fp8_unpack4(q0.y, d1);
#pragma unroll
    for (int j = 0; j < 4; ++j) {
      a[j] += ee0 * d0[j];
      a[4 + j] += ee0 * d1[j];
    }
    den += ee0;
  }
  float inv = 1.f / den;
  float4 bv0 = ((const float4*)b2)[lane * 2 + 0];
  float4 bv1 = ((const float4*)b2)[lane * 2 + 1];
  float v[8];
  v[0] = fmaf(a[0], inv, bv0.x); v[1] = fmaf(a[1], inv, bv0.y);
  v[2] = fmaf(a[2], inv, bv0.z); v[3] = fmaf(a[3], inv, bv0.w);
  v[4] = fmaf(a[4], inv, bv1.x); v[5] = fmaf(a[5], inv, bv1.y);
  v[6] = fmaf(a[6], inv, bv1.z); v[7] = fmaf(a[7], inv, bv1.w);
  float m = v[0];
#pragma unroll
  for (int j = 1; j < 8; ++j) m = fmaxf(m, v[j]);
#pragma unroll
  for (int k = 1; k < 8; k <<= 1) m = fmaxf(m, __shfl_xor(m, k));
  float ex = 0.f;
#pragma unroll
  for (int j = 0; j < 8; ++j) ex += __expf(v[j] - m);
#pragma unroll
  for (int k = 1; k < 8; k <<= 1) ex += __shfl_xor(ex, k);
  float lse = m + __logf(ex);
  float4 r0 = {v[0] - lse, v[1] - lse, v[2] - lse, v[3] - lse};
  float4 r1 = {v[4] - lse, v[5] - lse, v[6] - lse, v[7] - lse};
  float4* orow = (float4*)(out + (size_t)node * NC);
  orow[lane * 2 + 0] = r0;
  orow[lane * 2 + 1] = r1;
}

extern "C" void kernel_launch(void* const* d_in, const int* in_sizes, int n_in,
                              void* d_out, int out_size, void* d_ws,
                              size_t ws_size, hipStream_t stream) {
  const float* x = (const float*)d_in[0];
  const int* edge_index = (const int*)d_in[1];
  const float* W1 = (const float*)d_in[2];
  const float* a_src1 = (const float*)d_in[3];
  const float* a_dst1 = (const float*)d_in[4];
  const float* b1 = (const float*)d_in[5];
  const float* W2 = (const float*)d_in[6];
  const float* a_src2 = (const float*)d_in[7];
  const float* a_dst2 = (const float*)d_in[8];
  const float* b2 = (const float*)d_in[9];
  float* out = (float*)d_out;
  float* ws = (float*)d_ws;

  // workspace layout (float offsets), non-overlapping:
  ushort_t* x2b = (ushort_t*)ws;               // [0, 6.4M)   bf16 x2
  uint4* h8 = (uint4*)(ws + 6400000);          // [6.4M, 9.6M)  fp8 h1 (linear)
  uint2* h28 = (uint2*)(ws + 9600000);         // [9.6M, 11.2M) fp8 h2 (linear)
  float* asn1 = ws + 11200000;                 // [11.2M, 12.0M)
  float* adn1 = ws + 12000000;                 // [12.0M, 12.8M)
  float* asn2 = ws + 12800000;                 // [12.8M, 12.9M)
  float* adn2 = ws + 12900000;                 // [12.9M, 13.0M)
  ushort_t* WT1 = (ushort_t*)(ws + 13000000);  // 16384 bf16
  ushort_t* WT2 = (ushort_t*)(ws + 13010000);  // 8192 bf16
  int* rp = (int*)(ws + 13020000);             // NN+1
  int* col = rp + NN + 1;                      // EN
  int* staging = col + EN;                     // EN
  int* cnt = staging + EN;                     // NBUK*NBLK = 200192
  int* bucket_base = cnt + NBUK * NBLK;        // NBUK+1
  int* colsum = bucket_base + NBUK + 1;        // NBUK   (~17.0M floats)

  const int* srcA = edge_index;
  const int* dstA = edge_index + NE;

  // ---- CSR P1 (fused wt_prep) + parallel 2-level scan ----
  bucket_count_kernel<<<NBLK, 512, 0, stream>>>(dstA, cnt, W1, W2, WT1, WT2);
  scan_chunks_kernel<<<NBUK, 256, 0, stream>>>(cnt, colsum);
  scan_buckets_kernel<<<1, 1024, 0, stream>>>(colsum, bucket_base);
  // ---- scatter || gemm1 (horizontal fusion) ----
  scatter_gemm1_kernel<<<NBLK + (NN + 127) / 128, 512, 0, stream>>>(
      srcA, dstA, cnt, bucket_base, staging, x, WT1, a_src1, a_dst1,
      (uint2*)h8, asn1, adn1, NN);
  // ---- fused fine-CSR + layer-1 gather (1024 thr, 128 nodes in one pass) ----
  csr_gather1_kernel<<<NBUK, 1024, 0, stream>>>(staging, bucket_base, rp, col,
                                                asn1, adn1, h8, b1, x2b);
  // ---- layer 2 ----
  mfma_gemm2_kernel<<<(NN + 63) / 64, 256, 0, stream>>>(
      x2b, WT2, a_src2, a_dst2, (uint_t*)h28, asn2, adn2, NN);
  gather2_kernel<<<(NN + 31) / 32, 256, 0, stream>>>(rp, col, asn2, adn2, h28,
                                                     b2, out);
}

// Round 22
// 176.947 us; speedup vs baseline: 1.8500x; 1.0681x over previous
//
#include <hip/hip_runtime.h>

#define NN 100000
#define NE 1600000
#define EN (NE + NN)          // edges incl. self-loops
#define FIN 128
#define H1 8
#define C1 16
#define F1 128                // H1*C1
#define NC 64
#define NEG 0.2f

// ---- CSR-build multisplit parameters ----
#define BSH 7                 // bucket = dst >> BSH
#define BKN 128               // nodes per bucket
#define NBUK ((NN + BKN - 1) / BKN)   // 782
#define NBLK 256              // edge-chunk blocks for P1/P2
#define CHUNK ((EN + NBLK - 1) / NBLK) // 6641
#define CAPB 2688             // LDS col capacity per bucket (mean 2176 + 11s)
// XCD-aware chunk swizzle (kept from r17; neutral but harmless)
__device__ __forceinline__ int chunk_of_block(int b) {
  return (b & 7) * (NBLK / 8) + (b >> 3);
}

typedef unsigned short ushort_t;
typedef unsigned int uint_t;
typedef __attribute__((ext_vector_type(8))) short short8v;
typedef __attribute__((ext_vector_type(4))) float f32x4;
typedef __attribute__((ext_vector_type(2))) float f32x2;

union U8 { ushort_t u[8]; short8v v; uint4 q; };

__device__ __forceinline__ ushort_t f2bf(float f) {
  uint_t u = __builtin_bit_cast(uint_t, f);
  u += 0x7FFF + ((u >> 16) & 1);  // RNE
  return (ushort_t)(u >> 16);
}
__device__ __forceinline__ float bflo(uint_t u) {
  return __builtin_bit_cast(float, u << 16);
}
__device__ __forceinline__ float bfhi(uint_t u) {
  return __builtin_bit_cast(float, u & 0xFFFF0000u);
}

// ---------------- fp8 encode/decode (HW cvt preferred) -----------------------
#if __has_builtin(__builtin_amdgcn_cvt_pk_fp8_f32) && \
    __has_builtin(__builtin_amdgcn_cvt_pk_f32_fp8)
__device__ __forceinline__ uint_t fp8_pack4(float f0, float f1, float f2,
                                            float f3) {
  int p = 0;
  p = __builtin_amdgcn_cvt_pk_fp8_f32(f0, f1, p, false);
  p = __builtin_amdgcn_cvt_pk_fp8_f32(f2, f3, p, true);
  return (uint_t)p;
}
__device__ __forceinline__ void fp8_unpack4(uint_t w, float* o) {
  f32x2 d0 = __builtin_amdgcn_cvt_pk_f32_fp8((int)w, false);
  f32x2 d1 = __builtin_amdgcn_cvt_pk_f32_fp8((int)w, true);
  o[0] = d0.x; o[1] = d0.y; o[2] = d1.x; o[3] = d1.y;
}
#else
__device__ __forceinline__ uint_t fp8_enc1(float f) {
  uint_t u = __builtin_bit_cast(uint_t, f);
  uint_t s = (u >> 24) & 0x80u;
  int e = (int)((u >> 23) & 0xFF) - 127;
  if (e < -9) return s;
  if (e < -6) {
    float af = __builtin_bit_cast(float, u & 0x7FFFFFFFu);
    uint_t m = (uint_t)(af * 512.f + 0.5f);
    return s | m;
  }
  uint_t mant = u & 0x7FFFFF;
  uint_t keep = mant >> 20;
  uint_t rest = mant & 0xFFFFF;
  keep += (rest > 0x80000u) || (rest == 0x80000u && (keep & 1));
  uint_t ee = (uint_t)(e + 7);
  if (keep == 8) { keep = 0; ee += 1; }
  if (ee > 15 || (ee == 15 && keep > 6)) return s | 0x7E;
  return s | (ee << 3) | keep;
}
__device__ __forceinline__ float fp8_dec1(uint_t b) {
  uint_t s = (b & 0x80u) << 24;
  uint_t e = (b >> 3) & 15u, m = b & 7u;
  if (e == 0) {
    float v = (float)m * (1.0f / 512.0f);
    return __builtin_bit_cast(float, s | __builtin_bit_cast(uint_t, v));
  }
  return __builtin_bit_cast(float, s | ((e + 120u) << 23) | (m << 20));
}
__device__ __forceinline__ uint_t fp8_pack4(float f0, float f1, float f2,
                                            float f3) {
  return fp8_enc1(f0) | (fp8_enc1(f1) << 8) | (fp8_enc1(f2) << 16) |
         (fp8_enc1(f3) << 24);
}
__device__ __forceinline__ void fp8_unpack4(uint_t w, float* o) {
  o[0] = fp8_dec1(w & 0xFF); o[1] = fp8_dec1((w >> 8) & 0xFF);
  o[2] = fp8_dec1((w >> 16) & 0xFF); o[3] = fp8_dec1(w >> 24);
}
#endif

// ------------------ CSR P1: count (fused weight prep) ------------------------
__global__ __launch_bounds__(512) void bucket_count_kernel(
    const int* __restrict__ dstA, int* __restrict__ cnt,
    const float* __restrict__ W1, const float* __restrict__ W2,
    ushort_t* __restrict__ WT1, ushort_t* __restrict__ WT2) {
  __shared__ int histL[NBUK];
  int b = blockIdx.x, t = threadIdx.x;
  int gid = b * 512 + t;
  if (gid < 128 * 128) {
    int n = gid >> 7, k = gid & 127;
    int c = (n & 15) * 8 + (n >> 4);
    WT1[gid] = f2bf(W1[k * 128 + c]);
  } else if (gid < 128 * 128 + 64 * 128) {
    int j = gid - 128 * 128;
    int n = j >> 7, k = j & 127;
    int c = (n & 15) * 4 + (n >> 4);
    WT2[j] = f2bf(W2[k * 64 + c]);
  }
  for (int i = t; i < NBUK; i += 512) histL[i] = 0;
  __syncthreads();
  int ch = chunk_of_block(b);
  int e0 = ch * CHUNK, e1 = min(e0 + CHUNK, EN);
  for (int e = e0 + t; e < e1; e += 512) {
    int d = (e < NE) ? dstA[e] : (e - NE);
    atomicAdd(&histL[d >> BSH], 1);
  }
  __syncthreads();
  for (int i = t; i < NBUK; i += 512) cnt[i * NBLK + ch] = histL[i];
}

// scan A: per-bucket 256-wide LDS scan over chunks (in place), emit colsum.
__global__ __launch_bounds__(256) void scan_chunks_kernel(
    int* __restrict__ cnt, int* __restrict__ colsum) {
  __shared__ int sd[2][256];
  int j = blockIdx.x, t = threadIdx.x;
  int v = cnt[j * NBLK + t];
  sd[0][t] = v;
  __syncthreads();
  int sp = 0;
  for (int off = 1; off < 256; off <<= 1) {
    int val = sd[sp][t];
    if (t >= off) val += sd[sp][t - off];
    sd[sp ^ 1][t] = val;
    __syncthreads();
    sp ^= 1;
  }
  cnt[j * NBLK + t] = sd[sp][t] - v;  // exclusive within bucket
  if (t == 255) colsum[j] = sd[sp][255];
}

// scan B: one block scans the NBUK colsums into bucket_base (NBUK <= 1024).
__global__ __launch_bounds__(1024) void scan_buckets_kernel(
    const int* __restrict__ colsum, int* __restrict__ bucket_base) {
  __shared__ int sd[2][1024];
  int t = threadIdx.x;
  int v = (t < NBUK) ? colsum[t] : 0;
  sd[0][t] = v;
  __syncthreads();
  int sp = 0;
  for (int off = 1; off < 1024; off <<= 1) {
    int val = sd[sp][t];
    if (t >= off) val += sd[sp][t - off];
    sd[sp ^ 1][t] = val;
    __syncthreads();
    sp ^= 1;
  }
  if (t < NBUK) bucket_base[t] = sd[sp][t] - v;
  if (t == 0) bucket_base[NBUK] = EN;
}

// ---- CSR P2: edge scatter into bucket-contiguous staging (UNFUSED) ----------
__global__ __launch_bounds__(512) void bucket_scatter_kernel(
    const int* __restrict__ srcA, const int* __restrict__ dstA,
    const int* __restrict__ cnt, const int* __restrict__ bucket_base,
    int* __restrict__ staging) {
  __shared__ int cur[NBUK];
  int b = blockIdx.x, t = threadIdx.x;
  int ch = chunk_of_block(b);
  for (int i = t; i < NBUK; i += 512)
    cur[i] = cnt[i * NBLK + ch] + bucket_base[i];
  __syncthreads();
  int e0 = ch * CHUNK, e1 = min(e0 + CHUNK, EN);
  for (int e = e0 + t; e < e1; e += 512) {
    int s, d;
    if (e < NE) { s = srcA[e]; d = dstA[e]; } else { s = e - NE; d = s; }
    int pos = atomicAdd(&cur[d >> BSH], 1);
    staging[pos] = s | ((d & (BKN - 1)) << 17);
  }
}

// ---------- MFMA GEMM1 (fused layer-1 prep; no LDS; UNFUSED, 64 rows) --------
__global__ __launch_bounds__(256) void mfma_gemm1_kernel(
    const float* __restrict__ X, const ushort_t* __restrict__ WT1,
    const float* __restrict__ a_src, const float* __restrict__ a_dst,
    uint2* __restrict__ h8, float* __restrict__ asn, float* __restrict__ adn,
    int nrows) {
  const int tid = threadIdx.x;
  const int wave = tid >> 6, lane = tid & 63;
  const int row0 = blockIdx.x * 64 + wave * 16;
  const int rlo = lane & 15, khi = lane >> 4;  // khi in 0..3

  f32x4 acc[8];
#pragma unroll
  for (int n = 0; n < 8; ++n) acc[n] = (f32x4){0.f, 0.f, 0.f, 0.f};

#pragma unroll
  for (int ks = 0; ks < 4; ++ks) {
    const int kk = ks * 32 + khi * 8;
    int row = row0 + rlo;
    if (row >= nrows) row = nrows - 1;
    const float4* xp = (const float4*)(X + (size_t)row * 128 + kk);
    float4 u = xp[0], v = xp[1];
    U8 t;
    t.u[0] = f2bf(u.x); t.u[1] = f2bf(u.y); t.u[2] = f2bf(u.z); t.u[3] = f2bf(u.w);
    t.u[4] = f2bf(v.x); t.u[5] = f2bf(v.y); t.u[6] = f2bf(v.z); t.u[7] = f2bf(v.w);
    short8v a = t.v;
#pragma unroll
    for (int nf = 0; nf < 8; ++nf) {
      short8v b = *(const short8v*)(WT1 + (nf * 16 + rlo) * 128 + kk);
      acc[nf] = __builtin_amdgcn_mfma_f32_16x16x32_bf16(a, b, acc[nf], 0, 0, 0);
    }
  }
  const float4* as4 = (const float4*)a_src;
  const float4* ad4 = (const float4*)a_dst;
  float4 as0 = as4[rlo * 2], as1 = as4[rlo * 2 + 1];
  float4 ad0 = ad4[rlo * 2], ad1 = ad4[rlo * 2 + 1];
  // C/D layout: col = lane&15, row = (lane>>4)*4 + reg  [m89-verified]
  int rbase = row0 + khi * 4;
#pragma unroll
  for (int r = 0; r < 4; ++r) {
    int row = rbase + r;
    bool ok = (row < nrows);
    uint2 pk;
    pk.x = fp8_pack4(acc[0][r], acc[1][r], acc[2][r], acc[3][r]);
    pk.y = fp8_pack4(acc[4][r], acc[5][r], acc[6][r], acc[7][r]);
    if (ok) h8[(size_t)row * 16 + rlo] = pk;
    float s = acc[0][r] * as0.x + acc[1][r] * as0.y +
              acc[2][r] * as0.z + acc[3][r] * as0.w +
              acc[4][r] * as1.x + acc[5][r] * as1.y +
              acc[6][r] * as1.z + acc[7][r] * as1.w;
    float d = acc[0][r] * ad0.x + acc[1][r] * ad0.y +
              acc[2][r] * ad0.z + acc[3][r] * ad0.w +
              acc[4][r] * ad1.x + acc[5][r] * ad1.y +
              acc[6][r] * ad1.z + acc[7][r] * ad1.w;
    s += __shfl_xor(s, 1);
    d += __shfl_xor(d, 1);
    if (ok && (rlo & 1) == 0) {
      asn[row * 8 + (rlo >> 1)] = s;
      adn[row * 8 + (rlo >> 1)] = d;
    }
  }
}

// ---- FUSED fine-CSR + layer-1 gather: 1024 thr; col built in LDS ------------
__global__ __launch_bounds__(1024) void csr_gather1_kernel(
    const int* __restrict__ staging, const int* __restrict__ bucket_base,
    int* __restrict__ rp, int* __restrict__ col,
    const float* __restrict__ asn, const float* __restrict__ adn,
    const uint4* __restrict__ h8, const float* __restrict__ b1,
    ushort_t* __restrict__ x2) {
  __shared__ int degL[BKN];
  __shared__ int curL[BKN];
  __shared__ int startL[BKN + 1];   // LOCAL (within-bucket) offsets
  __shared__ int sdata[2][BKN];
  __shared__ int colL[CAPB];        // 10.5 KB
  int bk = blockIdx.x, t = threadIdx.x;
  int ebase = bucket_base[bk], eend = bucket_base[bk + 1];
  int ecnt = eend - ebase;
  bool fits = (ecnt <= CAPB);       // statistically always true
  if (t < BKN) degL[t] = 0;
  __syncthreads();
  for (int e = t; e < ecnt; e += 1024)
    atomicAdd(&degL[staging[ebase + e] >> 17], 1);
  __syncthreads();
  if (t < BKN) sdata[0][t] = degL[t];
  __syncthreads();
  int sp = 0;
  for (int off = 1; off < BKN; off <<= 1) {
    if (t < BKN) {
      int val = sdata[sp][t];
      if (t >= off) val += sdata[sp][t - off];
      sdata[sp ^ 1][t] = val;
    }
    __syncthreads();
    sp ^= 1;
  }
  if (t < BKN) {
    int ex = sdata[sp][t] - degL[t];  // local exclusive offset
    curL[t] = ex;
    startL[t] = ex;
    int node = bk * BKN + t;
    if (node < NN) rp[node] = ebase + ex;
  }
  if (t == 0) startL[BKN] = ecnt;
  if (bk == 0 && t == 0) rp[NN] = EN;
  __syncthreads();
  if (fits) {
    // cursor-scatter in LDS, then ONE coalesced global col write (for gather2)
    for (int e = t; e < ecnt; e += 1024) {
      int pk = staging[ebase + e];
      int pos = atomicAdd(&curL[pk >> 17], 1);
      colL[pos] = pk & 0x1FFFF;
    }
    __syncthreads();
    for (int e = t; e < ecnt; e += 1024) col[ebase + e] = colL[e];
  } else {
    for (int e = t; e < ecnt; e += 1024) {
      int pk = staging[ebase + e];
      int pos = atomicAdd(&curL[pk >> 17], 1);
      col[ebase + pos] = pk & 0x1FFFF;
    }
    __syncthreads();
  }
  __syncthreads();
  // ---- phase 2: gather1 (8 lanes/node, lane = head); all 128 nodes, 1 pass --
  int i = t >> 3, lane = t & 7;
  int node = bk * BKN + i;
  if (node >= NN) return;
  float aD = adn[node * 8 + lane];
  int p = startL[i], p1 = startL[i + 1];
  float a[16];
#pragma unroll
  for (int j = 0; j < 16; ++j) a[j] = 0.f;
  float den = 0.f;
  if (fits) {
    for (; p + 1 < p1; p += 2) {
      int s0 = colL[p], s1 = colL[p + 1];
      float e0 = asn[s0 * 8 + lane] + aD;
      float e1 = asn[s1 * 8 + lane] + aD;
      uint4 q0 = h8[(size_t)s0 * 8 + lane];
      uint4 q1 = h8[(size_t)s1 * 8 + lane];
      e0 = e0 > 0.f ? e0 : NEG * e0;
      e1 = e1 > 0.f ? e1 : NEG * e1;
      float ee0 = __expf(e0), ee1 = __expf(e1);
      float d0[4], d1[4], d2[4], d3[4];
      fp8_unpack4(q0.x, d0); fp8_unpack4(q0.y, d1);
      fp8_unpack4(q0.z, d2); fp8_unpack4(q0.w, d3);
      float g0[4], g1[4], g2[4], g3[4];
      fp8_unpack4(q1.x, g0); fp8_unpack4(q1.y, g1);
      fp8_unpack4(q1.z, g2); fp8_unpack4(q1.w, g3);
#pragma unroll
      for (int j = 0; j < 4; ++j) {
        a[j]      += ee0 * d0[j] + ee1 * g0[j];
        a[4 + j]  += ee0 * d1[j] + ee1 * g1[j];
        a[8 + j]  += ee0 * d2[j] + ee1 * g2[j];
        a[12 + j] += ee0 * d3[j] + ee1 * g3[j];
      }
      den += ee0 + ee1;
    }
    if (p < p1) {
      int s0 = colL[p];
      float e0 = asn[s0 * 8 + lane] + aD;
      uint4 q0 = h8[(size_t)s0 * 8 + lane];
      e0 = e0 > 0.f ? e0 : NEG * e0;
      float ee0 = __expf(e0);
      float d0[4], d1[4], d2[4], d3[4];
      fp8_unpack4(q0.x, d0); fp8_unpack4(q0.y, d1);
      fp8_unpack4(q0.z, d2); fp8_unpack4(q0.w, d3);
#pragma unroll
      for (int j = 0; j < 4; ++j) {
        a[j] += ee0 * d0[j];
        a[4 + j] += ee0 * d1[j];
        a[8 + j] += ee0 * d2[j];
        a[12 + j] += ee0 * d3[j];
      }
      den += ee0;
    }
  } else {
    const int* cg = col + ebase;
    for (; p < p1; ++p) {
      int s0 = cg[p];
      float e0 = asn[s0 * 8 + lane] + aD;
      uint4 q0 = h8[(size_t)s0 * 8 + lane];
      e0 = e0 > 0.f ? e0 : NEG * e0;
      float ee0 = __expf(e0);
      float d0[4], d1[4], d2[4], d3[4];
      fp8_unpack4(q0.x, d0); fp8_unpack4(q0.y, d1);
      fp8_unpack4(q0.z, d2); fp8_unpack4(q0.w, d3);
#pragma unroll
      for (int j = 0; j < 4; ++j) {
        a[j] += ee0 * d0[j];
        a[4 + j] += ee0 * d1[j];
        a[8 + j] += ee0 * d2[j];
        a[12 + j] += ee0 * d3[j];
      }
      den += ee0;
    }
  }
  float inv = 1.f / den;
  const float4* b4 = (const float4*)b1;  // channels 16*lane + 0..15
  U8 t0, t1;
#pragma unroll
  for (int h = 0; h < 4; ++h) {
    float4 bv = b4[lane * 4 + h];
    float o0 = fmaf(a[h * 4 + 0], inv, bv.x);
    float o1 = fmaf(a[h * 4 + 1], inv, bv.y);
    float o2 = fmaf(a[h * 4 + 2], inv, bv.z);
    float o3 = fmaf(a[h * 4 + 3], inv, bv.w);
    o0 = o0 > 0.f ? o0 : __expf(o0) - 1.f;
    o1 = o1 > 0.f ? o1 : __expf(o1) - 1.f;
    o2 = o2 > 0.f ? o2 : __expf(o2) - 1.f;
    o3 = o3 > 0.f ? o3 : __expf(o3) - 1.f;
    U8& tt = (h < 2) ? t0 : t1;
    int base = (h & 1) * 4;
    tt.u[base + 0] = f2bf(o0); tt.u[base + 1] = f2bf(o1);
    tt.u[base + 2] = f2bf(o2); tt.u[base + 3] = f2bf(o3);
  }
  uint4* xr = (uint4*)(x2 + (size_t)node * F1);  // row = 8 uint4
  xr[lane * 2 + 0] = t0.q;
  xr[lane * 2 + 1] = t1.q;
}

// ---------- MFMA GEMM2 (fused layer-2 prep; no LDS, B from WT2) --------------
__global__ __launch_bounds__(256) void mfma_gemm2_kernel(
    const ushort_t* __restrict__ X2, const ushort_t* __restrict__ WT2,
    const float* __restrict__ a_src, const float* __restrict__ a_dst,
    uint_t* __restrict__ h28, float* __restrict__ asn, float* __restrict__ adn,
    int nrows) {
  const int tid = threadIdx.x;
  const int wave = tid >> 6, lane = tid & 63;
  const int row0 = blockIdx.x * 64 + wave * 16;
  const int rlo = lane & 15, khi = lane >> 4;

  f32x4 acc[4];
#pragma unroll
  for (int n = 0; n < 4; ++n) acc[n] = (f32x4){0.f, 0.f, 0.f, 0.f};

#pragma unroll
  for (int ks = 0; ks < 4; ++ks) {
    const int kk = ks * 32 + khi * 8;
    int row = row0 + rlo;
    if (row >= nrows) row = nrows - 1;
    U8 t;
    t.q = *(const uint4*)(X2 + (size_t)row * 128 + kk);
    short8v a = t.v;
#pragma unroll
    for (int nf = 0; nf < 4; ++nf) {
      short8v b = *(const short8v*)(WT2 + (nf * 16 + rlo) * 128 + kk);
      acc[nf] = __builtin_amdgcn_mfma_f32_16x16x32_bf16(a, b, acc[nf], 0, 0, 0);
    }
  }
  float4 as = ((const float4*)a_src)[rlo];
  float4 ad = ((const float4*)a_dst)[rlo];
  int rbase = row0 + khi * 4;
#pragma unroll
  for (int r = 0; r < 4; ++r) {
    int row = rbase + r;
    bool ok = (row < nrows);
    uint_t pk = fp8_pack4(acc[0][r], acc[1][r], acc[2][r], acc[3][r]);
    if (ok) h28[(size_t)row * 16 + rlo] = pk;
    float s = acc[0][r] * as.x + acc[1][r] * as.y +
              acc[2][r] * as.z + acc[3][r] * as.w;
    float d = acc[0][r] * ad.x + acc[1][r] * ad.y +
              acc[2][r] * ad.z + acc[3][r] * ad.w;
    s += __shfl_xor(s, 1); s += __shfl_xor(s, 2);
    s += __shfl_xor(s, 4); s += __shfl_xor(s, 8);
    d += __shfl_xor(d, 1); d += __shfl_xor(d, 2);
    d += __shfl_xor(d, 4); d += __shfl_xor(d, 8);
    if (ok && rlo == 0) { asn[row] = s; adn[row] = d; }
  }
}

// ------ layer-2 gather: 8 lanes/node, 2-edge unroll + log_softmax ------------
__global__ __launch_bounds__(256) void gather2_kernel(
    const int* __restrict__ rp, const int* __restrict__ col,
    const float* __restrict__ asn, const float* __restrict__ adn,
    const uint2* __restrict__ h28, const float* __restrict__ b2,
    float* __restrict__ out) {
  int node = (blockIdx.x << 5) + (threadIdx.x >> 3);
  if (node >= NN) return;
  int lane = threadIdx.x & 7;
  float aD = adn[node];
  int p = rp[node], p1 = rp[node + 1];
  float a[8];
#pragma unroll
  for (int j = 0; j < 8; ++j) a[j] = 0.f;
  float den = 0.f;

  for (; p + 1 < p1; p += 2) {
    int s0 = col[p], s1 = col[p + 1];
    float e0 = asn[s0] + aD;
    float e1 = asn[s1] + aD;
    uint2 q0 = h28[(size_t)s0 * 8 + lane];
    uint2 q1 = h28[(size_t)s1 * 8 + lane];
    e0 = e0 > 0.f ? e0 : NEG * e0;
    e1 = e1 > 0.f ? e1 : NEG * e1;
    float ee0 = __expf(e0), ee1 = __expf(e1);
    float d0[4], d1[4], g0[4], g1[4];
    fp8_unpack4(q0.x, d0); fp8_unpack4(q0.y, d1);
    fp8_unpack4(q1.x, g0); fp8_unpack4(q1.y, g1);
#pragma unroll
    for (int j = 0; j < 4; ++j) {
      a[j] += ee0 * d0[j] + ee1 * g0[j];
      a[4 + j] += ee0 * d1[j] + ee1 * g1[j];
    }
    den += ee0 + ee1;
  }
  if (p < p1) {
    int s0 = col[p];
    float e0 = asn[s0] + aD;
    uint2 q0 = h28[(size_t)s0 * 8 + lane];
    e0 = e0 > 0.f ? e0 : NEG * e0;
    float ee0 = __expf(e0);
    float d0[4], d1[4];
    fp8_unpack4(q0.x, d0); fp8_unpack4(q0.y, d1);
#pragma unroll
    for (int j = 0; j < 4; ++j) {
      a[j] += ee0 * d0[j];
      a[4 + j] += ee0 * d1[j];
    }
    den += ee0;
  }
  float inv = 1.f / den;
  float4 bv0 = ((const float4*)b2)[lane * 2 + 0];
  float4 bv1 = ((const float4*)b2)[lane * 2 + 1];
  float v[8];
  v[0] = fmaf(a[0], inv, bv0.x); v[1] = fmaf(a[1], inv, bv0.y);
  v[2] = fmaf(a[2], inv, bv0.z); v[3] = fmaf(a[3], inv, bv0.w);
  v[4] = fmaf(a[4], inv, bv1.x); v[5] = fmaf(a[5], inv, bv1.y);
  v[6] = fmaf(a[6], inv, bv1.z); v[7] = fmaf(a[7], inv, bv1.w);
  float m = v[0];
#pragma unroll
  for (int j = 1; j < 8; ++j) m = fmaxf(m, v[j]);
#pragma unroll
  for (int k = 1; k < 8; k <<= 1) m = fmaxf(m, __shfl_xor(m, k));
  float ex = 0.f;
#pragma unroll
  for (int j = 0; j < 8; ++j) ex += __expf(v[j] - m);
#pragma unroll
  for (int k = 1; k < 8; k <<= 1) ex += __shfl_xor(ex, k);
  float lse = m + __logf(ex);
  float4 r0 = {v[0] - lse, v[1] - lse, v[2] - lse, v[3] - lse};
  float4 r1 = {v[4] - lse, v[5] - lse, v[6] - lse, v[7] - lse};
  float4* orow = (float4*)(out + (size_t)node * NC);
  orow[lane * 2 + 0] = r0;
  orow[lane * 2 + 1] = r1;
}

extern "C" void kernel_launch(void* const* d_in, const int* in_sizes, int n_in,
                              void* d_out, int out_size, void* d_ws,
                              size_t ws_size, hipStream_t stream) {
  const float* x = (const float*)d_in[0];
  const int* edge_index = (const int*)d_in[1];
  const float* W1 = (const float*)d_in[2];
  const float* a_src1 = (const float*)d_in[3];
  const float* a_dst1 = (const float*)d_in[4];
  const float* b1 = (const float*)d_in[5];
  const float* W2 = (const float*)d_in[6];
  const float* a_src2 = (const float*)d_in[7];
  const float* a_dst2 = (const float*)d_in[8];
  const float* b2 = (const float*)d_in[9];
  float* out = (float*)d_out;
  float* ws = (float*)d_ws;

  // workspace layout (float offsets), non-overlapping:
  ushort_t* x2b = (ushort_t*)ws;               // [0, 6.4M)   bf16 x2
  uint4* h8 = (uint4*)(ws + 6400000);          // [6.4M, 9.6M)  fp8 h1 (linear)
  uint2* h28 = (uint2*)(ws + 9600000);         // [9.6M, 11.2M) fp8 h2 (linear)
  float* asn1 = ws + 11200000;                 // [11.2M, 12.0M)
  float* adn1 = ws + 12000000;                 // [12.0M, 12.8M)
  float* asn2 = ws + 12800000;                 // [12.8M, 12.9M)
  float* adn2 = ws + 12900000;                 // [12.9M, 13.0M)
  ushort_t* WT1 = (ushort_t*)(ws + 13000000);  // 16384 bf16
  ushort_t* WT2 = (ushort_t*)(ws + 13010000);  // 8192 bf16
  int* rp = (int*)(ws + 13020000);             // NN+1
  int* col = rp + NN + 1;                      // EN
  int* staging = col + EN;                     // EN
  int* cnt = staging + EN;                     // NBUK*NBLK = 200192
  int* bucket_base = cnt + NBUK * NBLK;        // NBUK+1
  int* colsum = bucket_base + NBUK + 1;        // NBUK   (~17.0M floats)

  const int* srcA = edge_index;
  const int* dstA = edge_index + NE;

  // ---- CSR P1 (fused wt_prep) + parallel 2-level scan ----
  bucket_count_kernel<<<NBLK, 512, 0, stream>>>(dstA, cnt, W1, W2, WT1, WT2);
  scan_chunks_kernel<<<NBUK, 256, 0, stream>>>(cnt, colsum);
  scan_buckets_kernel<<<1, 1024, 0, stream>>>(colsum, bucket_base);
  // ---- edge scatter (unfused for visibility) + gemm1 ----
  bucket_scatter_kernel<<<NBLK, 512, 0, stream>>>(srcA, dstA, cnt, bucket_base,
                                                  staging);
  mfma_gemm1_kernel<<<(NN + 63) / 64, 256, 0, stream>>>(
      x, WT1, a_src1, a_dst1, (uint2*)h8, asn1, adn1, NN);
  // ---- fused fine-CSR + layer-1 gather (col built in LDS) ----
  csr_gather1_kernel<<<NBUK, 1024, 0, stream>>>(staging, bucket_base, rp, col,
                                                asn1, adn1, h8, b1, x2b);
  // ---- layer 2 ----
  mfma_gemm2_kernel<<<(NN + 63) / 64, 256, 0, stream>>>(
      x2b, WT2, a_src2, a_dst2, (uint_t*)h28, asn2, adn2, NN);
  gather2_kernel<<<(NN + 31) / 32, 256, 0, stream>>>(rp, col, asn2, adn2, h28,
                                                     b2, out);
}